// Round 1
// baseline (452.410 us; speedup 1.0000x reference)
//
#include <hip/hip_runtime.h>

// ---------- types / helpers ----------
typedef __attribute__((ext_vector_type(8))) __bf16 bf16x8;
typedef __attribute__((ext_vector_type(8))) ushort u16x8;
typedef __attribute__((ext_vector_type(4))) float f32x4;

#define MFMA16(a, b, c) __builtin_amdgcn_mfma_f32_16x16x32_bf16(a, b, c, 0, 0, 0)

__device__ __forceinline__ ushort f2bf(float f) {
    union { float f; unsigned u; } v; v.f = f;
    unsigned r = v.u + 0x7FFFu + ((v.u >> 16) & 1u);
    return (ushort)(r >> 16);
}
__device__ __forceinline__ float bf2f(ushort b) {
    union { unsigned u; float f; } v; v.u = ((unsigned)b) << 16; return v.f;
}
__device__ __forceinline__ void gload_lds16(const void* g, void* l) {
    __builtin_amdgcn_global_load_lds((const __attribute__((address_space(1))) void*)g,
                                     (__attribute__((address_space(3))) void*)l, 16, 0, 0);
}

// ---------- fp32 -> bf16 convert ----------
__global__ void cvt_f32_bf16(const float* __restrict__ in, ushort* __restrict__ out, int n4) {
    int i = blockIdx.x * blockDim.x + threadIdx.x;
    if (i >= n4) return;
    float4 v = ((const float4*)in)[i];
    ushort4 o;
    o.x = f2bf(v.x); o.y = f2bf(v.y); o.z = f2bf(v.z); o.w = f2bf(v.w);
    ((ushort4*)out)[i] = o;
}

// ---------- RoPE tables: [2048][32] cos/sin fp32 ----------
__global__ void rope_table_k(float* __restrict__ cosT, float* __restrict__ sinT) {
    int id = blockIdx.x * 256 + threadIdx.x;   // 65536 total
    int l = id >> 5, i = id & 31;
    float freq = __expf(-(float)i * (9.210340371976184f / 32.0f)); // ln(10000)=9.2103
    float ph = (float)l * freq;
    cosT[id] = cosf(ph);
    sinT[id] = sinf(ph);
}

// ---------- RoPE apply on qkv bf16 buffer [4096][3072]; Q scaled by 1/8 ----------
__global__ void rope_apply_k(ushort* __restrict__ qkv, const float* __restrict__ cosT,
                             const float* __restrict__ sinT) {
    int id = blockIdx.x * 256 + threadIdx.x;   // 4096*40*32 = 5242880
    int i = id & 31;
    int hh = (id >> 5) % 40;                   // 0..31 = Q heads, 32..39 = K heads
    int row = id / 1280;
    int l = row & 2047;
    size_t base = (size_t)row * 3072 + (hh < 32 ? hh * 64 : 2048 + (hh - 32) * 64);
    float c = cosT[(l << 5) + i], s = sinT[(l << 5) + i];
    float v1 = bf2f(qkv[base + i]), v2 = bf2f(qkv[base + 32 + i]);
    float scale = (hh < 32) ? 0.125f : 1.0f;   // fold 1/sqrt(64) into Q
    qkv[base + i]      = f2bf((c * v1 - s * v2) * scale);
    qkv[base + 32 + i] = f2bf((c * v2 + s * v1) * scale);
}

// ---------- transpose V: qkv[row][2560 + kh*64 + d] -> vt[(b*8+kh)*64 + d][l] ----------
__global__ void vtrans_k(const ushort* __restrict__ qkv, ushort* __restrict__ vt) {
    __shared__ __align__(16) ushort tile[64][72];   // +8 pad breaks bank conflicts
    int t = threadIdx.x;
    int l0 = blockIdx.x * 64, kh = blockIdx.y, b = blockIdx.z;
    int tr = t >> 3, tc = (t & 7) * 8;
#pragma unroll
    for (int i = 0; i < 2; ++i) {
        int l = i * 32 + tr;
        u16x8 v = *(const u16x8*)(qkv + (size_t)(b * 2048 + l0 + l) * 3072 + 2560 + kh * 64 + tc);
#pragma unroll
        for (int j = 0; j < 8; ++j) tile[tc + j][l] = v[j];
    }
    __syncthreads();
#pragma unroll
    for (int i = 0; i < 2; ++i) {
        int d = i * 32 + tr;
        u16x8 v = *(const u16x8*)&tile[d][tc];
        *(u16x8*)(vt + (size_t)((b * 8 + kh) * 64 + d) * 2048 + l0 + tc) = v;
    }
}

// ---------- GEMM C[M,N] = A[M,K] * B[N,K]^T, bf16 in, bf16 or fp32 out ----------
// m97 structure: 128x128 tile, BK=64, 4 waves each owning 64x64, global_load_lds w=16.
template <int F32OUT>
__global__ __launch_bounds__(256) void gemm_bt(const ushort* __restrict__ A,
                                               const ushort* __restrict__ B,
                                               void* __restrict__ Cp, int M, int N, int K) {
    __shared__ __align__(16) ushort As[128 * 64];
    __shared__ __align__(16) ushort Bs[128 * 64];
    const int tid = threadIdx.x, lane = tid & 63, wid = tid >> 6;
    const int m0 = blockIdx.y * 128, n0 = blockIdx.x * 128;
    const int wr = wid >> 1, wc = wid & 1;
    const int lr = lane & 15, lg = lane >> 4;
    const int srow = tid >> 3, scol = (tid & 7) * 8;
    f32x4 acc[4][4] = {};
    for (int k0 = 0; k0 < K; k0 += 64) {
#pragma unroll
        for (int i = 0; i < 4; ++i) {
            gload_lds16(A + (size_t)(m0 + i * 32 + srow) * K + k0 + scol,
                        (char*)As + i * 4096 + wid * 1024);
            gload_lds16(B + (size_t)(n0 + i * 32 + srow) * K + k0 + scol,
                        (char*)Bs + i * 4096 + wid * 1024);
        }
        __syncthreads();
#pragma unroll
        for (int kk = 0; kk < 2; ++kk) {
            bf16x8 af[4], bfr[4];
#pragma unroll
            for (int mi = 0; mi < 4; ++mi)
                af[mi] = *(const bf16x8*)&As[(wr * 64 + mi * 16 + lr) * 64 + kk * 32 + lg * 8];
#pragma unroll
            for (int ni = 0; ni < 4; ++ni)
                bfr[ni] = *(const bf16x8*)&Bs[(wc * 64 + ni * 16 + lr) * 64 + kk * 32 + lg * 8];
#pragma unroll
            for (int mi = 0; mi < 4; ++mi)
#pragma unroll
                for (int ni = 0; ni < 4; ++ni)
                    acc[mi][ni] = MFMA16(af[mi], bfr[ni], acc[mi][ni]);
        }
        __syncthreads();
    }
    // C/D layout: col = lane&15, row = (lane>>4)*4 + reg   [m89/m91 verified]
    const int r0 = m0 + wr * 64 + lg * 4;
    const int c0 = n0 + wc * 64 + lr;
    if (F32OUT) {
        float* C = (float*)Cp;
#pragma unroll
        for (int mi = 0; mi < 4; ++mi)
#pragma unroll
            for (int ni = 0; ni < 4; ++ni)
#pragma unroll
                for (int r = 0; r < 4; ++r)
                    C[(size_t)(r0 + mi * 16 + r) * N + c0 + ni * 16] = acc[mi][ni][r];
    } else {
        ushort* C = (ushort*)Cp;
#pragma unroll
        for (int mi = 0; mi < 4; ++mi)
#pragma unroll
            for (int ni = 0; ni < 4; ++ni)
#pragma unroll
                for (int r = 0; r < 4; ++r)
                    C[(size_t)(r0 + mi * 16 + r) * N + c0 + ni * 16] = f2bf(acc[mi][ni][r]);
    }
}

// ---------- flash attention, causal GQA ----------
// grid (32 q-tiles, 32 heads, 2 batch); block 256 = 4 waves; each wave owns 16 q rows.
__global__ __launch_bounds__(256) void attn_k(const ushort* __restrict__ qkv,
                                              const ushort* __restrict__ vt,
                                              ushort* __restrict__ attn) {
    __shared__ __align__(16) ushort Ks[64 * 64];      // [kv][d]
    __shared__ __align__(16) ushort Vs[64 * 64];      // [d][kv]  (V^T)
    __shared__ __align__(16) ushort Ps[4][16 * 64];   // per-wave P [q][kv]
    const int tid = threadIdx.x, lane = tid & 63, wid = tid >> 6;
    const int qt = blockIdx.x, h = blockIdx.y, b = blockIdx.z;
    const int kh = h >> 2;
    const int qbase = qt * 64;
    const int lr = lane & 15, lg = lane >> 4;
    // Q fragments (held in registers across the kv loop); Q already scaled by 1/8
    bf16x8 qf[2];
    {
        const ushort* qp = qkv + (size_t)(b * 2048 + qbase + wid * 16 + lr) * 3072 + h * 64;
        qf[0] = *(const bf16x8*)(qp + lg * 8);
        qf[1] = *(const bf16x8*)(qp + 32 + lg * 8);
    }
    float m[4], lsum[4];
    f32x4 o[4] = {};
#pragma unroll
    for (int r = 0; r < 4; ++r) { m[r] = -1e30f; lsum[r] = 0.f; }
    const int srow = tid >> 3, scol = (tid & 7) * 8;

    for (int it = 0; it <= qt; ++it) {
        const int kv0 = it * 64;
#pragma unroll
        for (int i = 0; i < 2; ++i) {
            gload_lds16(qkv + (size_t)(b * 2048 + kv0 + i * 32 + srow) * 3072 + 2048 + kh * 64 + scol,
                        (char*)Ks + i * 4096 + wid * 1024);
            gload_lds16(vt + (size_t)((b * 8 + kh) * 64 + i * 32 + srow) * 2048 + kv0 + scol,
                        (char*)Vs + i * 4096 + wid * 1024);
        }
        __syncthreads();
        // S = Q K^T : [16 q][64 kv] per wave
        f32x4 s[4] = {};
#pragma unroll
        for (int kk = 0; kk < 2; ++kk)
#pragma unroll
            for (int nf = 0; nf < 4; ++nf) {
                bf16x8 kf = *(const bf16x8*)&Ks[(nf * 16 + lr) * 64 + kk * 32 + lg * 8];
                s[nf] = MFMA16(qf[kk], kf, s[nf]);
            }
        if (kv0 == qbase) {   // diagonal tile causal mask
#pragma unroll
            for (int nf = 0; nf < 4; ++nf)
#pragma unroll
                for (int r = 0; r < 4; ++r) {
                    int qrow = wid * 16 + lg * 4 + r;
                    int kcol = nf * 16 + lr;
                    if (kcol > qrow) s[nf][r] = -1e30f;
                }
        }
        // online softmax, rows live on 16-lane groups
        float alpha[4];
#pragma unroll
        for (int r = 0; r < 4; ++r) {
            float mx = fmaxf(fmaxf(s[0][r], s[1][r]), fmaxf(s[2][r], s[3][r]));
            mx = fmaxf(mx, __shfl_xor(mx, 1));
            mx = fmaxf(mx, __shfl_xor(mx, 2));
            mx = fmaxf(mx, __shfl_xor(mx, 4));
            mx = fmaxf(mx, __shfl_xor(mx, 8));
            float mn = fmaxf(m[r], mx);
            alpha[r] = __expf(m[r] - mn);
            m[r] = mn;
            float rs = 0.f;
#pragma unroll
            for (int nf = 0; nf < 4; ++nf) {
                float p = __expf(s[nf][r] - mn);
                s[nf][r] = p;
                rs += p;
            }
            rs += __shfl_xor(rs, 1); rs += __shfl_xor(rs, 2);
            rs += __shfl_xor(rs, 4); rs += __shfl_xor(rs, 8);
            lsum[r] = lsum[r] * alpha[r] + rs;
#pragma unroll
            for (int nf = 0; nf < 4; ++nf) o[nf][r] *= alpha[r];
        }
        // P -> LDS (bf16), C-layout scatter
#pragma unroll
        for (int nf = 0; nf < 4; ++nf)
#pragma unroll
            for (int r = 0; r < 4; ++r)
                Ps[wid][(lg * 4 + r) * 64 + nf * 16 + lr] = f2bf(s[nf][r]);
        // O += P V  (A-frag from Ps, B-frag from transposed Vs — clean b128 reads)
#pragma unroll
        for (int kk = 0; kk < 2; ++kk) {
            bf16x8 pf = *(const bf16x8*)&Ps[wid][lr * 64 + kk * 32 + lg * 8];
#pragma unroll
            for (int nf = 0; nf < 4; ++nf) {
                bf16x8 vf = *(const bf16x8*)&Vs[(nf * 16 + lr) * 64 + kk * 32 + lg * 8];
                o[nf] = MFMA16(pf, vf, o[nf]);
            }
        }
        __syncthreads();
    }
    // epilogue: divide by row sums, write bf16 [b*L+q][h*64+d]
    const size_t orow = (size_t)(b * 2048 + qbase + wid * 16 + lg * 4);
#pragma unroll
    for (int nf = 0; nf < 4; ++nf) {
        int col = h * 64 + nf * 16 + lr;
#pragma unroll
        for (int r = 0; r < 4; ++r)
            attn[(orow + r) * 2048 + col] = f2bf(o[nf][r] * (1.f / lsum[r]));
    }
}

// ---------- launch ----------
extern "C" void kernel_launch(void* const* d_in, const int* in_sizes, int n_in,
                              void* d_out, int out_size, void* d_ws, size_t ws_size,
                              hipStream_t stream) {
    const float* x  = (const float*)d_in[0];
    const float* wq = (const float*)d_in[1];
    const float* wk = (const float*)d_in[2];
    const float* wv = (const float*)d_in[3];
    const float* wo = (const float*)d_in[4];
    float* out = (float*)d_out;
    char* ws = (char*)d_ws;

    // workspace layout (bytes)
    ushort* xb   = (ushort*)(ws);                 // 4096x2048 bf16 = 16 MB
    ushort* wcat = (ushort*)(ws + 16777216);      // 3072x2048 bf16 = 12 MB (wq|wk|wv rows)
    ushort* wob  = (ushort*)(ws + 29360128);      // 2048x2048 bf16 = 8 MB
    ushort* qkv  = (ushort*)(ws + 37748736);      // 4096x3072 bf16 = 24 MB
    ushort* vt   = (ushort*)(ws + 62914560);      // 2*8*64 x 2048 bf16 = 4 MB
    ushort* attn = (ushort*)(ws + 67108864);      // 4096x2048 bf16 = 16 MB
    float*  cosT = (float*)(ws + 83886080);       // 2048*32 f32
    float*  sinT = (float*)(ws + 84148224);       // 2048*32 f32   (end 84,410,368)

    // 1) converts fp32 -> bf16
    {
        int n4;
        n4 = 8388608 >> 2; cvt_f32_bf16<<<(n4 + 255) / 256, 256, 0, stream>>>(x, xb, n4);
        n4 = 4194304 >> 2; cvt_f32_bf16<<<(n4 + 255) / 256, 256, 0, stream>>>(wq, wcat, n4);
        n4 = 1048576 >> 2; cvt_f32_bf16<<<(n4 + 255) / 256, 256, 0, stream>>>(wk, wcat + 4194304, n4);
        n4 = 1048576 >> 2; cvt_f32_bf16<<<(n4 + 255) / 256, 256, 0, stream>>>(wv, wcat + 5242880, n4);
        n4 = 4194304 >> 2; cvt_f32_bf16<<<(n4 + 255) / 256, 256, 0, stream>>>(wo, wob, n4);
    }
    // 2) rope tables
    rope_table_k<<<256, 256, 0, stream>>>(cosT, sinT);
    // 3) fused QKV projection: [4096,2048] x [3072,2048]^T -> qkv bf16
    gemm_bt<0><<<dim3(24, 32), 256, 0, stream>>>(xb, wcat, qkv, 4096, 3072, 2048);
    // 4) RoPE on Q (scaled 1/8) and K
    rope_apply_k<<<20480, 256, 0, stream>>>(qkv, cosT, sinT);
    // 5) V transpose per head
    vtrans_k<<<dim3(32, 8, 2), 256, 0, stream>>>(qkv, vt);
    // 6) flash attention
    attn_k<<<dim3(32, 32, 2), 256, 0, stream>>>(qkv, vt, attn);
    // 7) output projection -> fp32 d_out
    gemm_bt<1><<<dim3(16, 32), 256, 0, stream>>>(attn, wob, out, 4096, 2048, 2048);
}

// Round 2
// 376.976 us; speedup vs baseline: 1.2001x; 1.2001x over previous
//
#include <hip/hip_runtime.h>

// ---------- types / helpers ----------
typedef __attribute__((ext_vector_type(8))) __bf16 bf16x8;
typedef __attribute__((ext_vector_type(8))) ushort u16x8;
typedef __attribute__((ext_vector_type(4))) float f32x4;

#define MFMA16(a, b, c) __builtin_amdgcn_mfma_f32_16x16x32_bf16(a, b, c, 0, 0, 0)

__device__ __forceinline__ ushort f2bf(float f) {
    union { float f; unsigned u; } v; v.f = f;
    unsigned r = v.u + 0x7FFFu + ((v.u >> 16) & 1u);
    return (ushort)(r >> 16);
}
__device__ __forceinline__ float bf2f(ushort b) {
    union { unsigned u; float f; } v; v.u = ((unsigned)b) << 16; return v.f;
}
__device__ __forceinline__ void gload_lds16(const void* g, void* l) {
    __builtin_amdgcn_global_load_lds((const __attribute__((address_space(1))) void*)g,
                                     (__attribute__((address_space(3))) void*)l, 16, 0, 0);
}

// swizzled LDS element index for an 8-element (16B) group: row-major [*, 64] bf16,
// group g (0..7) of row `row` lives at slot g ^ (row & 7).   [T2 st-swizzle]
__device__ __forceinline__ int swz8(int row, int g) {
    return row * 64 + (((g) ^ (row & 7)) << 3);
}

// stage a 64x64 bf16 tile (global row stride rs elements) into linear LDS with
// pre-swizzled SOURCE so that swz8() reads are conflict-free. 2 gloads/thread.
__device__ __forceinline__ void stage64(const ushort* __restrict__ g, int rs,
                                        char* lds, int tid) {
    const int r = tid >> 3;                 // 0..31
    const int c8 = ((tid & 7) ^ (r & 7)) << 3;  // swizzled source column group
    const int wid = tid >> 6;
    gload_lds16(g + (size_t)r * rs + c8, lds + wid * 1024);
    gload_lds16(g + (size_t)(r + 32) * rs + c8, lds + 4096 + wid * 1024);
}

// ---------- fp32 -> bf16 convert ----------
__global__ void cvt_f32_bf16(const float* __restrict__ in, ushort* __restrict__ out, int n4) {
    int i = blockIdx.x * blockDim.x + threadIdx.x;
    if (i >= n4) return;
    float4 v = ((const float4*)in)[i];
    ushort4 o;
    o.x = f2bf(v.x); o.y = f2bf(v.y); o.z = f2bf(v.z); o.w = f2bf(v.w);
    ((ushort4*)out)[i] = o;
}

// ---------- RoPE tables: [2048][32] cos/sin fp32 ----------
__global__ void rope_table_k(float* __restrict__ cosT, float* __restrict__ sinT) {
    int id = blockIdx.x * 256 + threadIdx.x;   // 65536 total
    int l = id >> 5, i = id & 31;
    float freq = __expf(-(float)i * (9.210340371976184f / 32.0f)); // ln(10000)=9.2103
    float ph = (float)l * freq;
    cosT[id] = cosf(ph);
    sinT[id] = sinf(ph);
}

// ---------- RoPE apply on qkv bf16 buffer [4096][3072]; Q scaled by 1/8 ----------
__global__ void rope_apply_k(ushort* __restrict__ qkv, const float* __restrict__ cosT,
                             const float* __restrict__ sinT) {
    int id = blockIdx.x * 256 + threadIdx.x;   // 4096*40*32 = 5242880
    int i = id & 31;
    int hh = (id >> 5) % 40;                   // 0..31 = Q heads, 32..39 = K heads
    int row = id / 1280;
    int l = row & 2047;
    size_t base = (size_t)row * 3072 + (hh < 32 ? hh * 64 : 2048 + (hh - 32) * 64);
    float c = cosT[(l << 5) + i], s = sinT[(l << 5) + i];
    float v1 = bf2f(qkv[base + i]), v2 = bf2f(qkv[base + 32 + i]);
    float scale = (hh < 32) ? 0.125f : 1.0f;   // fold 1/sqrt(64) into Q
    qkv[base + i]      = f2bf((c * v1 - s * v2) * scale);
    qkv[base + 32 + i] = f2bf((c * v2 + s * v1) * scale);
}

// ---------- transpose V: qkv[row][2560 + kh*64 + d] -> vt[(b*8+kh)*64 + d][l] ----------
__global__ void vtrans_k(const ushort* __restrict__ qkv, ushort* __restrict__ vt) {
    __shared__ __align__(16) ushort tile[64][72];   // +8 pad breaks bank conflicts
    int t = threadIdx.x;
    int l0 = blockIdx.x * 64, kh = blockIdx.y, b = blockIdx.z;
    int tr = t >> 3, tc = (t & 7) * 8;
#pragma unroll
    for (int i = 0; i < 2; ++i) {
        int l = i * 32 + tr;
        u16x8 v = *(const u16x8*)(qkv + (size_t)(b * 2048 + l0 + l) * 3072 + 2560 + kh * 64 + tc);
#pragma unroll
        for (int j = 0; j < 8; ++j) tile[tc + j][l] = v[j];
    }
    __syncthreads();
#pragma unroll
    for (int i = 0; i < 2; ++i) {
        int d = i * 32 + tr;
        u16x8 v = *(const u16x8*)&tile[d][tc];
        *(u16x8*)(vt + (size_t)((b * 8 + kh) * 64 + d) * 2048 + l0 + tc) = v;
    }
}

// ---------- GEMM C[M,N] = A[M,K] * B[N,K]^T, bf16 in, bf16 or fp32 out ----------
// m97 structure: 128x128 tile, BK=64, 4 waves each owning 64x64, global_load_lds w=16.
template <int F32OUT>
__global__ __launch_bounds__(256) void gemm_bt(const ushort* __restrict__ A,
                                               const ushort* __restrict__ B,
                                               void* __restrict__ Cp, int M, int N, int K) {
    __shared__ __align__(16) ushort As[128 * 64];
    __shared__ __align__(16) ushort Bs[128 * 64];
    const int tid = threadIdx.x, lane = tid & 63, wid = tid >> 6;
    const int m0 = blockIdx.y * 128, n0 = blockIdx.x * 128;
    const int wr = wid >> 1, wc = wid & 1;
    const int lr = lane & 15, lg = lane >> 4;
    const int srow = tid >> 3, scol = (tid & 7) * 8;
    f32x4 acc[4][4] = {};
    for (int k0 = 0; k0 < K; k0 += 64) {
#pragma unroll
        for (int i = 0; i < 4; ++i) {
            gload_lds16(A + (size_t)(m0 + i * 32 + srow) * K + k0 + scol,
                        (char*)As + i * 4096 + wid * 1024);
            gload_lds16(B + (size_t)(n0 + i * 32 + srow) * K + k0 + scol,
                        (char*)Bs + i * 4096 + wid * 1024);
        }
        __syncthreads();
#pragma unroll
        for (int kk = 0; kk < 2; ++kk) {
            bf16x8 af[4], bfr[4];
#pragma unroll
            for (int mi = 0; mi < 4; ++mi)
                af[mi] = *(const bf16x8*)&As[(wr * 64 + mi * 16 + lr) * 64 + kk * 32 + lg * 8];
#pragma unroll
            for (int ni = 0; ni < 4; ++ni)
                bfr[ni] = *(const bf16x8*)&Bs[(wc * 64 + ni * 16 + lr) * 64 + kk * 32 + lg * 8];
#pragma unroll
            for (int mi = 0; mi < 4; ++mi)
#pragma unroll
                for (int ni = 0; ni < 4; ++ni)
                    acc[mi][ni] = MFMA16(af[mi], bfr[ni], acc[mi][ni]);
        }
        __syncthreads();
    }
    // C/D layout: col = lane&15, row = (lane>>4)*4 + reg   [m89/m91 verified]
    const int r0 = m0 + wr * 64 + lg * 4;
    const int c0 = n0 + wc * 64 + lr;
    if (F32OUT) {
        float* C = (float*)Cp;
#pragma unroll
        for (int mi = 0; mi < 4; ++mi)
#pragma unroll
            for (int ni = 0; ni < 4; ++ni)
#pragma unroll
                for (int r = 0; r < 4; ++r)
                    C[(size_t)(r0 + mi * 16 + r) * N + c0 + ni * 16] = acc[mi][ni][r];
    } else {
        ushort* C = (ushort*)Cp;
#pragma unroll
        for (int mi = 0; mi < 4; ++mi)
#pragma unroll
            for (int ni = 0; ni < 4; ++ni)
#pragma unroll
                for (int r = 0; r < 4; ++r)
                    C[(size_t)(r0 + mi * 16 + r) * N + c0 + ni * 16] = f2bf(acc[mi][ni][r]);
    }
}

// ---------- flash attention, causal GQA ----------
// grid (32 q-tiles, 32 heads, 2 batch); block 256 = 4 waves; each wave owns 16 q rows.
// Double-buffered K/V staging (counted vmcnt, raw barriers), T2-swizzled LDS, setprio.
__global__ __launch_bounds__(256) void attn_k(const ushort* __restrict__ qkv,
                                              const ushort* __restrict__ vt,
                                              ushort* __restrict__ attn) {
    __shared__ __align__(16) ushort Ks[2][64 * 64];   // [kv][d], swizzled
    __shared__ __align__(16) ushort Vs[2][64 * 64];   // [d][kv]  (V^T), swizzled
    __shared__ __align__(16) ushort Ps[4][16 * 64];   // per-wave P [q][kv], swizzled
    const int tid = threadIdx.x, lane = tid & 63, wid = tid >> 6;
    const int qt = 31 - blockIdx.x;                   // longest blocks launch first
    const int h = blockIdx.y, b = blockIdx.z;
    const int kh = h >> 2;
    const int qbase = qt * 64;
    const int lr = lane & 15, lg = lane >> 4;
    // Q fragments (held in registers across the kv loop); Q already scaled by 1/8
    bf16x8 qf[2];
    {
        const ushort* qp = qkv + (size_t)(b * 2048 + qbase + wid * 16 + lr) * 3072 + h * 64;
        qf[0] = *(const bf16x8*)(qp + lg * 8);
        qf[1] = *(const bf16x8*)(qp + 32 + lg * 8);
    }
    float m[4], lsum[4];
    f32x4 o[4] = {};
#pragma unroll
    for (int r = 0; r < 4; ++r) { m[r] = -1e30f; lsum[r] = 0.f; }

    const ushort* Kg = qkv + (size_t)(b * 2048) * 3072 + 2048 + kh * 64;  // rows: kv, stride 3072
    const ushort* Vg = vt + (size_t)((b * 8 + kh) * 64) * 2048;           // rows: d,  stride 2048
    ushort* PsW = Ps[wid];

    // prologue: stage tile 0 into buffer 0
    stage64(Kg, 3072, (char*)Ks[0], tid);
    stage64(Vg, 2048, (char*)Vs[0], tid);

    for (int it = 0; it <= qt; ++it) {
        const int c = it & 1;
        if (it < qt) {  // prefetch next tile into the other buffer (issued before compute)
            const int kv1 = (it + 1) * 64;
            stage64(Kg + (size_t)kv1 * 3072, 3072, (char*)Ks[c ^ 1], tid);
            stage64(Vg + kv1, 2048, (char*)Vs[c ^ 1], tid);
            asm volatile("s_waitcnt vmcnt(4)" ::: "memory");  // current tile landed; 4 newest stay in flight
        } else {
            asm volatile("s_waitcnt vmcnt(0)" ::: "memory");
        }
        __builtin_amdgcn_s_barrier();

        const ushort* Kc = Ks[c];
        const ushort* Vc = Vs[c];
        // S = Q K^T : [16 q][64 kv] per wave
        f32x4 s[4] = {};
        __builtin_amdgcn_s_setprio(1);
#pragma unroll
        for (int kk = 0; kk < 2; ++kk)
#pragma unroll
            for (int nf = 0; nf < 4; ++nf) {
                bf16x8 kf = *(const bf16x8*)&Kc[swz8(nf * 16 + lr, kk * 4 + lg)];
                s[nf] = MFMA16(qf[kk], kf, s[nf]);
            }
        __builtin_amdgcn_s_setprio(0);
        if (it == qt) {   // diagonal tile causal mask
#pragma unroll
            for (int nf = 0; nf < 4; ++nf)
#pragma unroll
                for (int r = 0; r < 4; ++r) {
                    int qrow = wid * 16 + lg * 4 + r;
                    int kcol = nf * 16 + lr;
                    if (kcol > qrow) s[nf][r] = -1e30f;
                }
        }
        // online softmax, rows live on 16-lane groups
        float alpha[4];
#pragma unroll
        for (int r = 0; r < 4; ++r) {
            float mx = fmaxf(fmaxf(s[0][r], s[1][r]), fmaxf(s[2][r], s[3][r]));
            mx = fmaxf(mx, __shfl_xor(mx, 1));
            mx = fmaxf(mx, __shfl_xor(mx, 2));
            mx = fmaxf(mx, __shfl_xor(mx, 4));
            mx = fmaxf(mx, __shfl_xor(mx, 8));
            float mn = fmaxf(m[r], mx);
            alpha[r] = __expf(m[r] - mn);
            m[r] = mn;
            float rs = 0.f;
#pragma unroll
            for (int nf = 0; nf < 4; ++nf) {
                float p = __expf(s[nf][r] - mn);
                s[nf][r] = p;
                rs += p;
            }
            rs += __shfl_xor(rs, 1); rs += __shfl_xor(rs, 2);
            rs += __shfl_xor(rs, 4); rs += __shfl_xor(rs, 8);
            lsum[r] = lsum[r] * alpha[r] + rs;
#pragma unroll
            for (int nf = 0; nf < 4; ++nf) o[nf][r] *= alpha[r];
        }
        // P -> LDS (bf16), swizzled C-layout scatter (per-wave buffer, no barrier needed)
#pragma unroll
        for (int nf = 0; nf < 4; ++nf)
#pragma unroll
            for (int r = 0; r < 4; ++r) {
                int row = lg * 4 + r, col = nf * 16 + lr;
                PsW[row * 64 + (((col >> 3) ^ (row & 7)) << 3) + (col & 7)] = f2bf(s[nf][r]);
            }
        // O += P V  (A-frag from Ps, B-frag from V^T; swizzled b128 reads)
        __builtin_amdgcn_s_setprio(1);
#pragma unroll
        for (int kk = 0; kk < 2; ++kk) {
            bf16x8 pf = *(const bf16x8*)&PsW[swz8(lr, kk * 4 + lg)];
#pragma unroll
            for (int nf = 0; nf < 4; ++nf) {
                bf16x8 vf = *(const bf16x8*)&Vc[swz8(nf * 16 + lr, kk * 4 + lg)];
                o[nf] = MFMA16(pf, vf, o[nf]);
            }
        }
        __builtin_amdgcn_s_setprio(0);
        __builtin_amdgcn_s_barrier();   // all reads of buf c done before it+1 overwrites it
    }
    // epilogue: divide by row sums, write bf16 [b*L+q][h*64+d]
    const size_t orow = (size_t)(b * 2048 + qbase + wid * 16 + lg * 4);
#pragma unroll
    for (int nf = 0; nf < 4; ++nf) {
        int col = h * 64 + nf * 16 + lr;
#pragma unroll
        for (int r = 0; r < 4; ++r)
            attn[(orow + r) * 2048 + col] = f2bf(o[nf][r] * (1.f / lsum[r]));
    }
}

// ---------- launch ----------
extern "C" void kernel_launch(void* const* d_in, const int* in_sizes, int n_in,
                              void* d_out, int out_size, void* d_ws, size_t ws_size,
                              hipStream_t stream) {
    const float* x  = (const float*)d_in[0];
    const float* wq = (const float*)d_in[1];
    const float* wk = (const float*)d_in[2];
    const float* wv = (const float*)d_in[3];
    const float* wo = (const float*)d_in[4];
    float* out = (float*)d_out;
    char* ws = (char*)d_ws;

    // workspace layout (bytes)
    ushort* xb   = (ushort*)(ws);                 // 4096x2048 bf16 = 16 MB
    ushort* wcat = (ushort*)(ws + 16777216);      // 3072x2048 bf16 = 12 MB (wq|wk|wv rows)
    ushort* wob  = (ushort*)(ws + 29360128);      // 2048x2048 bf16 = 8 MB
    ushort* qkv  = (ushort*)(ws + 37748736);      // 4096x3072 bf16 = 24 MB
    ushort* vt   = (ushort*)(ws + 62914560);      // 2*8*64 x 2048 bf16 = 4 MB
    ushort* attn = (ushort*)(ws + 67108864);      // 4096x2048 bf16 = 16 MB
    float*  cosT = (float*)(ws + 83886080);       // 2048*32 f32
    float*  sinT = (float*)(ws + 84148224);       // 2048*32 f32   (end 84,410,368)

    // 1) converts fp32 -> bf16
    {
        int n4;
        n4 = 8388608 >> 2; cvt_f32_bf16<<<(n4 + 255) / 256, 256, 0, stream>>>(x, xb, n4);
        n4 = 4194304 >> 2; cvt_f32_bf16<<<(n4 + 255) / 256, 256, 0, stream>>>(wq, wcat, n4);
        n4 = 1048576 >> 2; cvt_f32_bf16<<<(n4 + 255) / 256, 256, 0, stream>>>(wk, wcat + 4194304, n4);
        n4 = 1048576 >> 2; cvt_f32_bf16<<<(n4 + 255) / 256, 256, 0, stream>>>(wv, wcat + 5242880, n4);
        n4 = 4194304 >> 2; cvt_f32_bf16<<<(n4 + 255) / 256, 256, 0, stream>>>(wo, wob, n4);
    }
    // 2) rope tables
    rope_table_k<<<256, 256, 0, stream>>>(cosT, sinT);
    // 3) fused QKV projection: [4096,2048] x [3072,2048]^T -> qkv bf16
    gemm_bt<0><<<dim3(24, 32), 256, 0, stream>>>(xb, wcat, qkv, 4096, 3072, 2048);
    // 4) RoPE on Q (scaled 1/8) and K
    rope_apply_k<<<20480, 256, 0, stream>>>(qkv, cosT, sinT);
    // 5) V transpose per head
    vtrans_k<<<dim3(32, 8, 2), 256, 0, stream>>>(qkv, vt);
    // 6) flash attention
    attn_k<<<dim3(32, 32, 2), 256, 0, stream>>>(qkv, vt, attn);
    // 7) output projection -> fp32 d_out
    gemm_bt<1><<<dim3(16, 32), 256, 0, stream>>>(attn, wob, out, 4096, 2048, 2048);
}

// Round 3
// 314.122 us; speedup vs baseline: 1.4402x; 1.2001x over previous
//
#include <hip/hip_runtime.h>

// ---------- types / helpers ----------
typedef __attribute__((ext_vector_type(8))) __bf16 bf16x8;
typedef __attribute__((ext_vector_type(8))) ushort u16x8;
typedef __attribute__((ext_vector_type(4))) float f32x4;
typedef __attribute__((ext_vector_type(16))) float f32x16;

#define MFMA16(a, b, c) __builtin_amdgcn_mfma_f32_16x16x32_bf16(a, b, c, 0, 0, 0)
#define MFMA32(a, b, c) __builtin_amdgcn_mfma_f32_32x32x16_bf16(a, b, c, 0, 0, 0)

__device__ __forceinline__ ushort f2bf(float f) {
    union { float f; unsigned u; } v; v.f = f;
    unsigned r = v.u + 0x7FFFu + ((v.u >> 16) & 1u);
    return (ushort)(r >> 16);
}
__device__ __forceinline__ float bf2f(ushort b) {
    union { unsigned u; float f; } v; v.u = ((unsigned)b) << 16; return v.f;
}
__device__ __forceinline__ int cvtpk(float lo, float hi) {   // packed bf16(lo)|bf16(hi)<<16
    int r; asm("v_cvt_pk_bf16_f32 %0, %1, %2" : "=v"(r) : "v"(lo), "v"(hi)); return r;
}
__device__ __forceinline__ void gload_lds16(const void* g, void* l) {
    __builtin_amdgcn_global_load_lds((const __attribute__((address_space(1))) void*)g,
                                     (__attribute__((address_space(3))) void*)l, 16, 0, 0);
}

// swizzled LDS element index: row-major [*,64] bf16; 16B group g of row lives at g^(row&7)
__device__ __forceinline__ int swz8(int row, int g) {
    return row * 64 + (((g) ^ (row & 7)) << 3);
}

// stage a 64x64 bf16 tile (global row stride rs) into linear LDS with pre-swizzled SOURCE
__device__ __forceinline__ void stage64(const ushort* __restrict__ g, int rs,
                                        char* lds, int tid) {
    const int r = tid >> 3;
    const int c8 = ((tid & 7) ^ (r & 7)) << 3;
    const int wid = tid >> 6;
    gload_lds16(g + (size_t)r * rs + c8, lds + wid * 1024);
    gload_lds16(g + (size_t)(r + 32) * rs + c8, lds + 4096 + wid * 1024);
}

// ---------- fp32 -> bf16 convert ----------
__global__ void cvt_f32_bf16(const float* __restrict__ in, ushort* __restrict__ out, int n4) {
    int i = blockIdx.x * blockDim.x + threadIdx.x;
    if (i >= n4) return;
    float4 v = ((const float4*)in)[i];
    ushort4 o;
    o.x = f2bf(v.x); o.y = f2bf(v.y); o.z = f2bf(v.z); o.w = f2bf(v.w);
    ((ushort4*)out)[i] = o;
}

// ---------- RoPE tables ----------
__global__ void rope_table_k(float* __restrict__ cosT, float* __restrict__ sinT) {
    int id = blockIdx.x * 256 + threadIdx.x;   // 65536 total
    int l = id >> 5, i = id & 31;
    float freq = __expf(-(float)i * (9.210340371976184f / 32.0f));
    float ph = (float)l * freq;
    cosT[id] = cosf(ph);
    sinT[id] = sinf(ph);
}

// ---------- RoPE apply; Q scaled by (1/8)*log2(e) so attn can use exp2 ----------
__global__ void rope_apply_k(ushort* __restrict__ qkv, const float* __restrict__ cosT,
                             const float* __restrict__ sinT) {
    int id = blockIdx.x * 256 + threadIdx.x;   // 4096*40*32
    int i = id & 31;
    int hh = (id >> 5) % 40;
    int row = id / 1280;
    int l = row & 2047;
    size_t base = (size_t)row * 3072 + (hh < 32 ? hh * 64 : 2048 + (hh - 32) * 64);
    float c = cosT[(l << 5) + i], s = sinT[(l << 5) + i];
    float v1 = bf2f(qkv[base + i]), v2 = bf2f(qkv[base + 32 + i]);
    float scale = (hh < 32) ? 0.18033688f : 1.0f;   // 0.125 * log2(e)
    qkv[base + i]      = f2bf((c * v1 - s * v2) * scale);
    qkv[base + 32 + i] = f2bf((c * v2 + s * v1) * scale);
}

// ---------- transpose V ----------
__global__ void vtrans_k(const ushort* __restrict__ qkv, ushort* __restrict__ vt) {
    __shared__ __align__(16) ushort tile[64][72];
    int t = threadIdx.x;
    int l0 = blockIdx.x * 64, kh = blockIdx.y, b = blockIdx.z;
    int tr = t >> 3, tc = (t & 7) * 8;
#pragma unroll
    for (int i = 0; i < 2; ++i) {
        int l = i * 32 + tr;
        u16x8 v = *(const u16x8*)(qkv + (size_t)(b * 2048 + l0 + l) * 3072 + 2560 + kh * 64 + tc);
#pragma unroll
        for (int j = 0; j < 8; ++j) tile[tc + j][l] = v[j];
    }
    __syncthreads();
#pragma unroll
    for (int i = 0; i < 2; ++i) {
        int d = i * 32 + tr;
        u16x8 v = *(const u16x8*)&tile[d][tc];
        *(u16x8*)(vt + (size_t)((b * 8 + kh) * 64 + d) * 2048 + l0 + tc) = v;
    }
}

// ---------- GEMM C[M,N] = A[M,K] * B[N,K]^T (m97 structure) ----------
template <int F32OUT>
__global__ __launch_bounds__(256) void gemm_bt(const ushort* __restrict__ A,
                                               const ushort* __restrict__ B,
                                               void* __restrict__ Cp, int M, int N, int K) {
    __shared__ __align__(16) ushort As[128 * 64];
    __shared__ __align__(16) ushort Bs[128 * 64];
    const int tid = threadIdx.x, lane = tid & 63, wid = tid >> 6;
    const int m0 = blockIdx.y * 128, n0 = blockIdx.x * 128;
    const int wr = wid >> 1, wc = wid & 1;
    const int lr = lane & 15, lg = lane >> 4;
    const int srow = tid >> 3, scol = (tid & 7) * 8;
    f32x4 acc[4][4] = {};
    for (int k0 = 0; k0 < K; k0 += 64) {
#pragma unroll
        for (int i = 0; i < 4; ++i) {
            gload_lds16(A + (size_t)(m0 + i * 32 + srow) * K + k0 + scol,
                        (char*)As + i * 4096 + wid * 1024);
            gload_lds16(B + (size_t)(n0 + i * 32 + srow) * K + k0 + scol,
                        (char*)Bs + i * 4096 + wid * 1024);
        }
        __syncthreads();
#pragma unroll
        for (int kk = 0; kk < 2; ++kk) {
            bf16x8 af[4], bfr[4];
#pragma unroll
            for (int mi = 0; mi < 4; ++mi)
                af[mi] = *(const bf16x8*)&As[(wr * 64 + mi * 16 + lr) * 64 + kk * 32 + lg * 8];
#pragma unroll
            for (int ni = 0; ni < 4; ++ni)
                bfr[ni] = *(const bf16x8*)&Bs[(wc * 64 + ni * 16 + lr) * 64 + kk * 32 + lg * 8];
#pragma unroll
            for (int mi = 0; mi < 4; ++mi)
#pragma unroll
                for (int ni = 0; ni < 4; ++ni)
                    acc[mi][ni] = MFMA16(af[mi], bfr[ni], acc[mi][ni]);
        }
        __syncthreads();
    }
    const int r0 = m0 + wr * 64 + lg * 4;
    const int c0 = n0 + wc * 64 + lr;
    if (F32OUT) {
        float* C = (float*)Cp;
#pragma unroll
        for (int mi = 0; mi < 4; ++mi)
#pragma unroll
            for (int ni = 0; ni < 4; ++ni)
#pragma unroll
                for (int r = 0; r < 4; ++r)
                    C[(size_t)(r0 + mi * 16 + r) * N + c0 + ni * 16] = acc[mi][ni][r];
    } else {
        ushort* C = (ushort*)Cp;
#pragma unroll
        for (int mi = 0; mi < 4; ++mi)
#pragma unroll
            for (int ni = 0; ni < 4; ++ni)
#pragma unroll
                for (int r = 0; r < 4; ++r)
                    C[(size_t)(r0 + mi * 16 + r) * N + c0 + ni * 16] = f2bf(acc[mi][ni][r]);
    }
}

// ---------- flash attention: swapped QK^T, in-register softmax (T12/T13), 32x32 MFMA ----------
// grid (16 q-blocks, 32 heads, 2 batch); block 256 = 4 waves; wave owns 32 q rows.
// Sm = mfma32(K,Q): lane owns q-col = lane&31, 32 kv values in regs (+partner half-lane).
__global__ __launch_bounds__(256) void attn_k(const ushort* __restrict__ qkv,
                                              const ushort* __restrict__ vt,
                                              ushort* __restrict__ attn) {
    __shared__ __align__(16) ushort smem[16384];   // Ks[2]:0/4096, Vs[2]:8192/12288 (32KB)
    const int tid = threadIdx.x, lane = tid & 63, wid = tid >> 6;
    const int hl = lane >> 5, lq = lane & 31;
    const int qt = 15 - blockIdx.x;               // longest blocks first
    const int head = blockIdx.y, b = blockIdx.z;
    const int kh = head >> 2;
    const int qb = qt << 7;
    const int qw0 = qb + wid * 32;
    const int q_lane = qw0 + lq;
    const int nt = 2 * qt + 2;

    // Q fragments: B-operand [col=q][k=d], d = j*16 + hl*8 + e
    bf16x8 qf[4];
    {
        const ushort* qp = qkv + (size_t)(b * 2048 + qw0 + lq) * 3072 + head * 64 + hl * 8;
#pragma unroll
        for (int j = 0; j < 4; ++j) qf[j] = *(const bf16x8*)(qp + j * 16);
    }
    f32x16 o0 = {}, o1 = {};     // O^T accum: d-tiles 0/1, col=q
    float m_ = -1e30f, lsum = 0.f;

    const ushort* Kg = qkv + (size_t)(b * 2048) * 3072 + 2048 + kh * 64;  // [kv][*] stride 3072
    const ushort* Vg = vt + (size_t)((b * 8 + kh) * 64) * 2048;           // [d][kv] stride 2048

    stage64(Kg, 3072, (char*)smem, tid);
    stage64(Vg, 2048, (char*)(smem + 8192), tid);

    for (int it = 0; it < nt; ++it) {
        const int c = it & 1;
        const int kv0 = it << 6;
        const ushort* Kc = smem + c * 4096;
        const ushort* Vc = smem + 8192 + c * 4096;
        if (it + 1 < nt) {
            stage64(Kg + (size_t)(kv0 + 64) * 3072, 3072, (char*)(smem + (c ^ 1) * 4096), tid);
            stage64(Vg + kv0 + 64, 2048, (char*)(smem + 8192 + (c ^ 1) * 4096), tid);
            asm volatile("s_waitcnt vmcnt(4)" ::: "memory");
        } else {
            asm volatile("s_waitcnt vmcnt(0)" ::: "memory");
        }
        __builtin_amdgcn_s_barrier();

        // S^T = K · Q^T : rows kv (2 subtiles), col q
        f32x16 s0 = {}, s1 = {};
        __builtin_amdgcn_s_setprio(1);
#pragma unroll
        for (int j = 0; j < 4; ++j) {
            bf16x8 k0 = *(const bf16x8*)&Kc[swz8(lq, j * 2 + hl)];
            bf16x8 k1 = *(const bf16x8*)&Kc[swz8(32 + lq, j * 2 + hl)];
            s0 = MFMA32(k0, qf[j], s0);
            s1 = MFMA32(k1, qf[j], s1);
        }
        __builtin_amdgcn_s_setprio(0);

        if (kv0 + 63 > qw0) {   // causal mask (wave-uniform branch)
#pragma unroll
            for (int i = 0; i < 16; ++i) {
                int kvr = (i & 3) + ((i >> 2) << 3) + (hl << 2) + kv0;  // kv row of reg i
                if (kvr > q_lane)      s0[i] = -1e30f;
                if (kvr + 32 > q_lane) s1[i] = -1e30f;
            }
        }
        // in-register softmax (log2 domain; scale folded into Q)
        float pmax = s0[0];
#pragma unroll
        for (int i = 1; i < 16; ++i) pmax = fmaxf(pmax, s0[i]);
#pragma unroll
        for (int i = 0; i < 16; ++i) pmax = fmaxf(pmax, s1[i]);
        {
            auto sw = __builtin_amdgcn_permlane32_swap(__float_as_int(pmax), __float_as_int(pmax), 0, 0);
            pmax = fmaxf(__int_as_float(sw[0]), __int_as_float(sw[1]));
        }
        if (!__all(pmax <= m_ + 8.0f)) {   // defer-max (T13)
            float mn = fmaxf(m_, pmax);
            float alpha = exp2f(m_ - mn);
            m_ = mn; lsum *= alpha;
#pragma unroll
            for (int i = 0; i < 16; ++i) { o0[i] *= alpha; o1[i] *= alpha; }
        }
        float rs = 0.f;
#pragma unroll
        for (int i = 0; i < 16; ++i) { s0[i] = exp2f(s0[i] - m_); rs += s0[i]; }
#pragma unroll
        for (int i = 0; i < 16; ++i) { s1[i] = exp2f(s1[i] - m_); rs += s1[i]; }
        {
            auto sw = __builtin_amdgcn_permlane32_swap(__float_as_int(rs), __float_as_int(rs), 0, 0);
            rs = __int_as_float(sw[0]) + __int_as_float(sw[1]);
        }
        lsum += rs;

        // P^T fragments: per 16-kv chunk, 4 cvt_pk + 2 permlane32_swap (T12)
        bf16x8 pf[4];
#pragma unroll
        for (int cc = 0; cc < 4; ++cc) {
            float p0, p1, p2, p3, p4, p5, p6, p7;
            if (cc == 0)      { p0=s0[0]; p1=s0[1]; p2=s0[2]; p3=s0[3]; p4=s0[4]; p5=s0[5]; p6=s0[6]; p7=s0[7]; }
            else if (cc == 1) { p0=s0[8]; p1=s0[9]; p2=s0[10]; p3=s0[11]; p4=s0[12]; p5=s0[13]; p6=s0[14]; p7=s0[15]; }
            else if (cc == 2) { p0=s1[0]; p1=s1[1]; p2=s1[2]; p3=s1[3]; p4=s1[4]; p5=s1[5]; p6=s1[6]; p7=s1[7]; }
            else              { p0=s1[8]; p1=s1[9]; p2=s1[10]; p3=s1[11]; p4=s1[12]; p5=s1[13]; p6=s1[14]; p7=s1[15]; }
            int pk01 = cvtpk(p0, p1), pk23 = cvtpk(p2, p3);
            int pk45 = cvtpk(p4, p5), pk67 = cvtpk(p6, p7);
            auto sA = __builtin_amdgcn_permlane32_swap(pk01, pk45, 0, 0);
            auto sB = __builtin_amdgcn_permlane32_swap(pk23, pk67, 0, 0);
            union { int w[4]; bf16x8 v; } u;
            u.w[0] = sA[0]; u.w[1] = sB[0]; u.w[2] = sA[1]; u.w[3] = sB[1];
            pf[cc] = u.v;
        }
        // O^T += V^T · P : A=V^T[d][kv] from LDS, B=P^T frag
        __builtin_amdgcn_s_setprio(1);
#pragma unroll
        for (int cc = 0; cc < 4; ++cc) {
            bf16x8 v0 = *(const bf16x8*)&Vc[swz8(lq, cc * 2 + hl)];
            bf16x8 v1 = *(const bf16x8*)&Vc[swz8(32 + lq, cc * 2 + hl)];
            o0 = MFMA32(v0, pf[cc], o0);
            o1 = MFMA32(v1, pf[cc], o1);
        }
        __builtin_amdgcn_s_setprio(0);
        __builtin_amdgcn_s_barrier();
    }

    // epilogue: O^T -> LDS transpose (per-wave region) -> coalesced b128 stores
    __syncthreads();
    ushort* sc = smem + wid * 2560;    // [32 q][80] bf16, 16B-aligned rows
    float inv = 1.0f / lsum;
#pragma unroll
    for (int i = 0; i < 16; i += 2) {
        int d0 = (i & 3) + ((i >> 2) << 3) + (hl << 2);
        *(int*)&sc[lq * 80 + d0]      = cvtpk(o0[i] * inv, o0[i + 1] * inv);
        *(int*)&sc[lq * 80 + d0 + 32] = cvtpk(o1[i] * inv, o1[i + 1] * inv);
    }
    __syncthreads();
    {
        const int q = lane >> 1, db = (lane & 1) << 5;
        const size_t orow = (size_t)(b * 2048 + qb + wid * 32 + q);
#pragma unroll
        for (int j = 0; j < 4; ++j) {
            u16x8 v = *(const u16x8*)&sc[q * 80 + db + j * 8];
            *(u16x8*)(attn + orow * 2048 + head * 64 + db + j * 8) = v;
        }
    }
}

// ---------- launch ----------
extern "C" void kernel_launch(void* const* d_in, const int* in_sizes, int n_in,
                              void* d_out, int out_size, void* d_ws, size_t ws_size,
                              hipStream_t stream) {
    const float* x  = (const float*)d_in[0];
    const float* wq = (const float*)d_in[1];
    const float* wk = (const float*)d_in[2];
    const float* wv = (const float*)d_in[3];
    const float* wo = (const float*)d_in[4];
    float* out = (float*)d_out;
    char* ws = (char*)d_ws;

    ushort* xb   = (ushort*)(ws);                 // 16 MB
    ushort* wcat = (ushort*)(ws + 16777216);      // 12 MB
    ushort* wob  = (ushort*)(ws + 29360128);      // 8 MB
    ushort* qkv  = (ushort*)(ws + 37748736);      // 24 MB
    ushort* vt   = (ushort*)(ws + 62914560);      // 4 MB
    ushort* attn = (ushort*)(ws + 67108864);      // 16 MB
    float*  cosT = (float*)(ws + 83886080);
    float*  sinT = (float*)(ws + 84148224);

    {
        int n4;
        n4 = 8388608 >> 2; cvt_f32_bf16<<<(n4 + 255) / 256, 256, 0, stream>>>(x, xb, n4);
        n4 = 4194304 >> 2; cvt_f32_bf16<<<(n4 + 255) / 256, 256, 0, stream>>>(wq, wcat, n4);
        n4 = 1048576 >> 2; cvt_f32_bf16<<<(n4 + 255) / 256, 256, 0, stream>>>(wk, wcat + 4194304, n4);
        n4 = 1048576 >> 2; cvt_f32_bf16<<<(n4 + 255) / 256, 256, 0, stream>>>(wv, wcat + 5242880, n4);
        n4 = 4194304 >> 2; cvt_f32_bf16<<<(n4 + 255) / 256, 256, 0, stream>>>(wo, wob, n4);
    }
    rope_table_k<<<256, 256, 0, stream>>>(cosT, sinT);
    gemm_bt<0><<<dim3(24, 32), 256, 0, stream>>>(xb, wcat, qkv, 4096, 3072, 2048);
    rope_apply_k<<<20480, 256, 0, stream>>>(qkv, cosT, sinT);
    vtrans_k<<<dim3(32, 8, 2), 256, 0, stream>>>(qkv, vt);
    attn_k<<<dim3(16, 32, 2), 256, 0, stream>>>(qkv, vt, attn);
    gemm_bt<1><<<dim3(16, 32), 256, 0, stream>>>(attn, wob, out, 4096, 2048, 2048);
}

// Round 4
// 259.679 us; speedup vs baseline: 1.7422x; 1.2097x over previous
//
#include <hip/hip_runtime.h>

// ---------- types / helpers ----------
typedef __attribute__((ext_vector_type(8))) __bf16 bf16x8;
typedef __attribute__((ext_vector_type(8))) ushort u16x8;
typedef __attribute__((ext_vector_type(4))) float f32x4;
typedef __attribute__((ext_vector_type(16))) float f32x16;

#define MFMA16(a, b, c) __builtin_amdgcn_mfma_f32_16x16x32_bf16(a, b, c, 0, 0, 0)
#define MFMA32(a, b, c) __builtin_amdgcn_mfma_f32_32x32x16_bf16(a, b, c, 0, 0, 0)

__device__ __forceinline__ ushort f2bf(float f) {
    union { float f; unsigned u; } v; v.f = f;
    unsigned r = v.u + 0x7FFFu + ((v.u >> 16) & 1u);
    return (ushort)(r >> 16);
}
__device__ __forceinline__ float bf2f(ushort b) {
    union { unsigned u; float f; } v; v.u = ((unsigned)b) << 16; return v.f;
}
__device__ __forceinline__ int cvtpk(float lo, float hi) {   // packed bf16(lo)|bf16(hi)<<16
    int r; asm("v_cvt_pk_bf16_f32 %0, %1, %2" : "=v"(r) : "v"(lo), "v"(hi)); return r;
}
__device__ __forceinline__ void gload_lds16(const void* g, void* l) {
    __builtin_amdgcn_global_load_lds((const __attribute__((address_space(1))) void*)g,
                                     (__attribute__((address_space(3))) void*)l, 16, 0, 0);
}

// swizzled LDS element index: row-major [*,64] bf16; 16B group g of row lives at g^(row&7)
__device__ __forceinline__ int swz8(int row, int g) {
    return row * 64 + (((g) ^ (row & 7)) << 3);
}

// stage a 64x64 bf16 tile (global row stride rs) into linear LDS with pre-swizzled SOURCE
__device__ __forceinline__ void stage64(const ushort* __restrict__ g, int rs,
                                        char* lds, int tid) {
    const int r = tid >> 3;
    const int c8 = ((tid & 7) ^ (r & 7)) << 3;
    const int wid = tid >> 6;
    gload_lds16(g + (size_t)r * rs + c8, lds + wid * 1024);
    gload_lds16(g + (size_t)(r + 32) * rs + c8, lds + 4096 + wid * 1024);
}

// ---------- fp32 -> bf16 convert ----------
__global__ void cvt_f32_bf16(const float* __restrict__ in, ushort* __restrict__ out, int n4) {
    int i = blockIdx.x * blockDim.x + threadIdx.x;
    if (i >= n4) return;
    float4 v = ((const float4*)in)[i];
    ushort4 o;
    o.x = f2bf(v.x); o.y = f2bf(v.y); o.z = f2bf(v.z); o.w = f2bf(v.w);
    ((ushort4*)out)[i] = o;
}

// ---------- RoPE tables ----------
__global__ void rope_table_k(float* __restrict__ cosT, float* __restrict__ sinT) {
    int id = blockIdx.x * 256 + threadIdx.x;   // 65536 total
    int l = id >> 5, i = id & 31;
    float freq = __expf(-(float)i * (9.210340371976184f / 32.0f));
    float ph = (float)l * freq;
    cosT[id] = cosf(ph);
    sinT[id] = sinf(ph);
}

// ---------- RoPE apply; Q scaled by (1/8)*log2(e) so attn can use exp2 ----------
__global__ void rope_apply_k(ushort* __restrict__ qkv, const float* __restrict__ cosT,
                             const float* __restrict__ sinT) {
    int id = blockIdx.x * 256 + threadIdx.x;   // 4096*40*32
    int i = id & 31;
    int hh = (id >> 5) % 40;
    int row = id / 1280;
    int l = row & 2047;
    size_t base = (size_t)row * 3072 + (hh < 32 ? hh * 64 : 2048 + (hh - 32) * 64);
    float c = cosT[(l << 5) + i], s = sinT[(l << 5) + i];
    float v1 = bf2f(qkv[base + i]), v2 = bf2f(qkv[base + 32 + i]);
    float scale = (hh < 32) ? 0.18033688f : 1.0f;   // 0.125 * log2(e)
    qkv[base + i]      = f2bf((c * v1 - s * v2) * scale);
    qkv[base + 32 + i] = f2bf((c * v2 + s * v1) * scale);
}

// ---------- transpose V ----------
__global__ void vtrans_k(const ushort* __restrict__ qkv, ushort* __restrict__ vt) {
    __shared__ __align__(16) ushort tile[64][72];
    int t = threadIdx.x;
    int l0 = blockIdx.x * 64, kh = blockIdx.y, b = blockIdx.z;
    int tr = t >> 3, tc = (t & 7) * 8;
#pragma unroll
    for (int i = 0; i < 2; ++i) {
        int l = i * 32 + tr;
        u16x8 v = *(const u16x8*)(qkv + (size_t)(b * 2048 + l0 + l) * 3072 + 2560 + kh * 64 + tc);
#pragma unroll
        for (int j = 0; j < 8; ++j) tile[tc + j][l] = v[j];
    }
    __syncthreads();
#pragma unroll
    for (int i = 0; i < 2; ++i) {
        int d = i * 32 + tr;
        u16x8 v = *(const u16x8*)&tile[d][tc];
        *(u16x8*)(vt + (size_t)((b * 8 + kh) * 64 + d) * 2048 + l0 + tc) = v;
    }
}

// ---------- GEMM C[M,N] = A[M,K] * B[N,K]^T (m97 structure) ----------
template <int F32OUT>
__global__ __launch_bounds__(256) void gemm_bt(const ushort* __restrict__ A,
                                               const ushort* __restrict__ B,
                                               void* __restrict__ Cp, int M, int N, int K) {
    __shared__ __align__(16) ushort As[128 * 64];
    __shared__ __align__(16) ushort Bs[128 * 64];
    const int tid = threadIdx.x, lane = tid & 63, wid = tid >> 6;
    const int m0 = blockIdx.y * 128, n0 = blockIdx.x * 128;
    const int wr = wid >> 1, wc = wid & 1;
    const int lr = lane & 15, lg = lane >> 4;
    const int srow = tid >> 3, scol = (tid & 7) * 8;
    f32x4 acc[4][4] = {};
    for (int k0 = 0; k0 < K; k0 += 64) {
#pragma unroll
        for (int i = 0; i < 4; ++i) {
            gload_lds16(A + (size_t)(m0 + i * 32 + srow) * K + k0 + scol,
                        (char*)As + i * 4096 + wid * 1024);
            gload_lds16(B + (size_t)(n0 + i * 32 + srow) * K + k0 + scol,
                        (char*)Bs + i * 4096 + wid * 1024);
        }
        __syncthreads();
#pragma unroll
        for (int kk = 0; kk < 2; ++kk) {
            bf16x8 af[4], bfr[4];
#pragma unroll
            for (int mi = 0; mi < 4; ++mi)
                af[mi] = *(const bf16x8*)&As[(wr * 64 + mi * 16 + lr) * 64 + kk * 32 + lg * 8];
#pragma unroll
            for (int ni = 0; ni < 4; ++ni)
                bfr[ni] = *(const bf16x8*)&Bs[(wc * 64 + ni * 16 + lr) * 64 + kk * 32 + lg * 8];
#pragma unroll
            for (int mi = 0; mi < 4; ++mi)
#pragma unroll
                for (int ni = 0; ni < 4; ++ni)
                    acc[mi][ni] = MFMA16(af[mi], bfr[ni], acc[mi][ni]);
        }
        __syncthreads();
    }
    const int r0 = m0 + wr * 64 + lg * 4;
    const int c0 = n0 + wc * 64 + lr;
    if (F32OUT) {
        float* C = (float*)Cp;
#pragma unroll
        for (int mi = 0; mi < 4; ++mi)
#pragma unroll
            for (int ni = 0; ni < 4; ++ni)
#pragma unroll
                for (int r = 0; r < 4; ++r)
                    C[(size_t)(r0 + mi * 16 + r) * N + c0 + ni * 16] = acc[mi][ni][r];
    } else {
        ushort* C = (ushort*)Cp;
#pragma unroll
        for (int mi = 0; mi < 4; ++mi)
#pragma unroll
            for (int ni = 0; ni < 4; ++ni)
#pragma unroll
                for (int r = 0; r < 4; ++r)
                    C[(size_t)(r0 + mi * 16 + r) * N + c0 + ni * 16] = f2bf(acc[mi][ni][r]);
    }
}

// ---------- flash attention: swapped QK^T, in-reg softmax, causal-PAIRED q-tiles ----------
// grid (8, 32, 2); block 256 = 4 waves. Block p processes q-tiles {15-p, p} sequentially:
// total kv-tile work = (2(15-p)+2) + (2p+2) = 34 for EVERY block -> perfectly balanced.
__global__ __launch_bounds__(256) void attn_k(const ushort* __restrict__ qkv,
                                              const ushort* __restrict__ vt,
                                              ushort* __restrict__ attn) {
    __shared__ __align__(16) ushort smem[16384];   // Ks[2]: bytes 0/8192, Vs[2]: 16384/24576
    const int tid = threadIdx.x, lane = tid & 63, wid = tid >> 6;
    const int hl = lane >> 5, lq = lane & 31;
    const int p = blockIdx.x;                     // 0..7
    const int head = blockIdx.y, b = blockIdx.z;
    const int kh = head >> 2;

    const ushort* Kg = qkv + (size_t)(b * 2048) * 3072 + 2048 + kh * 64;  // [kv][*] stride 3072
    const ushort* Vg = vt + (size_t)((b * 8 + kh) * 64) * 2048;           // [d][kv] stride 2048

    for (int ph = 0; ph < 2; ++ph) {
        const int qt = ph ? p : 15 - p;
        const int qb = qt << 7;
        const int qw0 = qb + wid * 32;
        const int q_lane = qw0 + lq;
        const int nt = 2 * qt + 2;

        // Q fragments: B-operand [col=q][k=d], d = j*16 + hl*8 + e
        bf16x8 qf[4];
        {
            const ushort* qp = qkv + (size_t)(b * 2048 + qw0 + lq) * 3072 + head * 64 + hl * 8;
#pragma unroll
            for (int j = 0; j < 4; ++j) qf[j] = *(const bf16x8*)(qp + j * 16);
        }
        f32x16 o0 = {}, o1 = {};     // O^T accum: d-tiles 0/1, col=q
        float m_ = -1e30f, lsum = 0.f;

        stage64(Kg, 3072, (char*)smem, tid);
        stage64(Vg, 2048, (char*)(smem + 8192), tid);

        for (int it = 0; it < nt; ++it) {
            const int c = it & 1;
            const int kv0 = it << 6;
            const ushort* Kc = smem + c * 4096;
            const ushort* Vc = smem + 8192 + c * 4096;
            if (it + 1 < nt) {
                stage64(Kg + (size_t)(kv0 + 64) * 3072, 3072, (char*)(smem + (c ^ 1) * 4096), tid);
                stage64(Vg + kv0 + 64, 2048, (char*)(smem + 8192 + (c ^ 1) * 4096), tid);
                asm volatile("s_waitcnt vmcnt(4)" ::: "memory");
            } else {
                asm volatile("s_waitcnt vmcnt(0)" ::: "memory");
            }
            __builtin_amdgcn_s_barrier();

            // S^T = K · Q^T : rows kv (2 subtiles), col q
            f32x16 s0 = {}, s1 = {};
            __builtin_amdgcn_s_setprio(1);
#pragma unroll
            for (int j = 0; j < 4; ++j) {
                bf16x8 k0 = *(const bf16x8*)&Kc[swz8(lq, j * 2 + hl)];
                bf16x8 k1 = *(const bf16x8*)&Kc[swz8(32 + lq, j * 2 + hl)];
                s0 = MFMA32(k0, qf[j], s0);
                s1 = MFMA32(k1, qf[j], s1);
            }
            __builtin_amdgcn_s_setprio(0);

            if (kv0 + 63 > qw0) {   // causal mask (wave-uniform branch)
#pragma unroll
                for (int i = 0; i < 16; ++i) {
                    int kvr = (i & 3) + ((i >> 2) << 3) + (hl << 2) + kv0;
                    if (kvr > q_lane)      s0[i] = -1e30f;
                    if (kvr + 32 > q_lane) s1[i] = -1e30f;
                }
            }
            // in-register softmax (log2 domain; scale folded into Q)
            float pmax = s0[0];
#pragma unroll
            for (int i = 1; i < 16; ++i) pmax = fmaxf(pmax, s0[i]);
#pragma unroll
            for (int i = 0; i < 16; ++i) pmax = fmaxf(pmax, s1[i]);
            {
                auto sw = __builtin_amdgcn_permlane32_swap(__float_as_int(pmax), __float_as_int(pmax), 0, 0);
                pmax = fmaxf(__int_as_float(sw[0]), __int_as_float(sw[1]));
            }
            if (!__all(pmax <= m_ + 8.0f)) {   // defer-max (T13)
                float mn = fmaxf(m_, pmax);
                float alpha = exp2f(m_ - mn);
                m_ = mn; lsum *= alpha;
#pragma unroll
                for (int i = 0; i < 16; ++i) { o0[i] *= alpha; o1[i] *= alpha; }
            }
            float rs = 0.f;
#pragma unroll
            for (int i = 0; i < 16; ++i) { s0[i] = exp2f(s0[i] - m_); rs += s0[i]; }
#pragma unroll
            for (int i = 0; i < 16; ++i) { s1[i] = exp2f(s1[i] - m_); rs += s1[i]; }
            {
                auto sw = __builtin_amdgcn_permlane32_swap(__float_as_int(rs), __float_as_int(rs), 0, 0);
                rs = __int_as_float(sw[0]) + __int_as_float(sw[1]);
            }
            lsum += rs;

            // P^T fragments: per 16-kv chunk, 4 cvt_pk + 2 permlane32_swap (T12)
            bf16x8 pf[4];
#pragma unroll
            for (int cc = 0; cc < 4; ++cc) {
                float p0, p1, p2, p3, p4, p5, p6, p7;
                if (cc == 0)      { p0=s0[0]; p1=s0[1]; p2=s0[2]; p3=s0[3]; p4=s0[4]; p5=s0[5]; p6=s0[6]; p7=s0[7]; }
                else if (cc == 1) { p0=s0[8]; p1=s0[9]; p2=s0[10]; p3=s0[11]; p4=s0[12]; p5=s0[13]; p6=s0[14]; p7=s0[15]; }
                else if (cc == 2) { p0=s1[0]; p1=s1[1]; p2=s1[2]; p3=s1[3]; p4=s1[4]; p5=s1[5]; p6=s1[6]; p7=s1[7]; }
                else              { p0=s1[8]; p1=s1[9]; p2=s1[10]; p3=s1[11]; p4=s1[12]; p5=s1[13]; p6=s1[14]; p7=s1[15]; }
                int pk01 = cvtpk(p0, p1), pk23 = cvtpk(p2, p3);
                int pk45 = cvtpk(p4, p5), pk67 = cvtpk(p6, p7);
                auto sA = __builtin_amdgcn_permlane32_swap(pk01, pk45, 0, 0);
                auto sB = __builtin_amdgcn_permlane32_swap(pk23, pk67, 0, 0);
                union { int w[4]; bf16x8 v; } u;
                u.w[0] = sA[0]; u.w[1] = sB[0]; u.w[2] = sA[1]; u.w[3] = sB[1];
                pf[cc] = u.v;
            }
            // O^T += V^T · P : A=V^T[d][kv] from LDS, B=P^T frag
            __builtin_amdgcn_s_setprio(1);
#pragma unroll
            for (int cc = 0; cc < 4; ++cc) {
                bf16x8 v0 = *(const bf16x8*)&Vc[swz8(lq, cc * 2 + hl)];
                bf16x8 v1 = *(const bf16x8*)&Vc[swz8(32 + lq, cc * 2 + hl)];
                o0 = MFMA32(v0, pf[cc], o0);
                o1 = MFMA32(v1, pf[cc], o1);
            }
            __builtin_amdgcn_s_setprio(0);
            __builtin_amdgcn_s_barrier();
        }

        // epilogue: O^T -> swizzled LDS transpose (per-wave 4KB in K-buffer area) -> b128 stores
        __syncthreads();
        ushort* sc = (ushort*)((char*)smem + wid * 4096);   // [32 q][64 d], XOR-group swizzled
        float inv = 1.0f / lsum;
#pragma unroll
        for (int i = 0; i < 16; i += 2) {
            int d0 = (i & 3) + ((i >> 2) << 3) + (hl << 2);
            int g0 = d0 >> 3, g1 = (d0 + 32) >> 3;
            *(int*)&sc[lq * 64 + ((g0 ^ (lq & 7)) << 3) + (d0 & 7)] = cvtpk(o0[i] * inv, o0[i + 1] * inv);
            *(int*)&sc[lq * 64 + ((g1 ^ (lq & 7)) << 3) + (d0 & 7)] = cvtpk(o1[i] * inv, o1[i + 1] * inv);
        }
        __syncthreads();
        {
            const int q = lane >> 1, db = (lane & 1) << 5;
            const size_t orow = (size_t)(b * 2048 + qb + wid * 32 + q);
#pragma unroll
            for (int j = 0; j < 4; ++j) {
                int g = (db >> 3) + j;
                u16x8 v = *(const u16x8*)&sc[q * 64 + ((g ^ (q & 7)) << 3)];
                *(u16x8*)(attn + orow * 2048 + head * 64 + g * 8) = v;
            }
        }
        __syncthreads();   // sc reads done before next phase re-stages this LDS
    }
}

// ---------- launch ----------
extern "C" void kernel_launch(void* const* d_in, const int* in_sizes, int n_in,
                              void* d_out, int out_size, void* d_ws, size_t ws_size,
                              hipStream_t stream) {
    const float* x  = (const float*)d_in[0];
    const float* wq = (const float*)d_in[1];
    const float* wk = (const float*)d_in[2];
    const float* wv = (const float*)d_in[3];
    const float* wo = (const float*)d_in[4];
    float* out = (float*)d_out;
    char* ws = (char*)d_ws;

    ushort* xb   = (ushort*)(ws);                 // 16 MB
    ushort* wcat = (ushort*)(ws + 16777216);      // 12 MB
    ushort* wob  = (ushort*)(ws + 29360128);      // 8 MB
    ushort* qkv  = (ushort*)(ws + 37748736);      // 24 MB
    ushort* vt   = (ushort*)(ws + 62914560);      // 4 MB
    ushort* attn = (ushort*)(ws + 67108864);      // 16 MB
    float*  cosT = (float*)(ws + 83886080);
    float*  sinT = (float*)(ws + 84148224);

    {
        int n4;
        n4 = 8388608 >> 2; cvt_f32_bf16<<<(n4 + 255) / 256, 256, 0, stream>>>(x, xb, n4);
        n4 = 4194304 >> 2; cvt_f32_bf16<<<(n4 + 255) / 256, 256, 0, stream>>>(wq, wcat, n4);
        n4 = 1048576 >> 2; cvt_f32_bf16<<<(n4 + 255) / 256, 256, 0, stream>>>(wk, wcat + 4194304, n4);
        n4 = 1048576 >> 2; cvt_f32_bf16<<<(n4 + 255) / 256, 256, 0, stream>>>(wv, wcat + 5242880, n4);
        n4 = 4194304 >> 2; cvt_f32_bf16<<<(n4 + 255) / 256, 256, 0, stream>>>(wo, wob, n4);
    }
    rope_table_k<<<256, 256, 0, stream>>>(cosT, sinT);
    gemm_bt<0><<<dim3(24, 32), 256, 0, stream>>>(xb, wcat, qkv, 4096, 3072, 2048);
    rope_apply_k<<<20480, 256, 0, stream>>>(qkv, cosT, sinT);
    vtrans_k<<<dim3(32, 8, 2), 256, 0, stream>>>(qkv, vt);
    attn_k<<<dim3(8, 32, 2), 256, 0, stream>>>(qkv, vt, attn);
    gemm_bt<1><<<dim3(16, 32), 256, 0, stream>>>(attn, wob, out, 4096, 2048, 2048);
}

// Round 5
// 244.406 us; speedup vs baseline: 1.8511x; 1.0625x over previous
//
#include <hip/hip_runtime.h>

// ---------- types / helpers ----------
typedef __attribute__((ext_vector_type(8))) __bf16 bf16x8;
typedef __attribute__((ext_vector_type(8))) ushort u16x8;
typedef __attribute__((ext_vector_type(4))) float f32x4;
typedef __attribute__((ext_vector_type(16))) float f32x16;

#define MFMA16(a, b, c) __builtin_amdgcn_mfma_f32_16x16x32_bf16(a, b, c, 0, 0, 0)
#define MFMA32(a, b, c) __builtin_amdgcn_mfma_f32_32x32x16_bf16(a, b, c, 0, 0, 0)

__device__ __forceinline__ ushort f2bf(float f) {
    union { float f; unsigned u; } v; v.f = f;
    unsigned r = v.u + 0x7FFFu + ((v.u >> 16) & 1u);
    return (ushort)(r >> 16);
}
__device__ __forceinline__ float bf2f(ushort b) {
    union { unsigned u; float f; } v; v.u = ((unsigned)b) << 16; return v.f;
}
__device__ __forceinline__ int cvtpk(float lo, float hi) {   // packed bf16(lo)|bf16(hi)<<16
    int r; asm("v_cvt_pk_bf16_f32 %0, %1, %2" : "=v"(r) : "v"(lo), "v"(hi)); return r;
}
__device__ __forceinline__ void gload_lds16(const void* g, void* l) {
    __builtin_amdgcn_global_load_lds((const __attribute__((address_space(1))) void*)g,
                                     (__attribute__((address_space(3))) void*)l, 16, 0, 0);
}

// swizzled LDS element index: row-major [*,64] bf16; 16B group g of row lives at g^(row&7)
__device__ __forceinline__ int swz8(int row, int g) {
    return row * 64 + (((g) ^ (row & 7)) << 3);
}

// stage a 64x64 bf16 tile (global row stride rs) into linear LDS with pre-swizzled SOURCE
__device__ __forceinline__ void stage64(const ushort* __restrict__ g, int rs,
                                        char* lds, int tid) {
    const int r = tid >> 3;
    const int c8 = ((tid & 7) ^ (r & 7)) << 3;
    const int wid = tid >> 6;
    gload_lds16(g + (size_t)r * rs + c8, lds + wid * 1024);
    gload_lds16(g + (size_t)(r + 32) * rs + c8, lds + 4096 + wid * 1024);
}

// ---------- fp32 -> bf16 convert ----------
__global__ void cvt_f32_bf16(const float* __restrict__ in, ushort* __restrict__ out, int n4) {
    int i = blockIdx.x * blockDim.x + threadIdx.x;
    if (i >= n4) return;
    float4 v = ((const float4*)in)[i];
    ushort4 o;
    o.x = f2bf(v.x); o.y = f2bf(v.y); o.z = f2bf(v.z); o.w = f2bf(v.w);
    ((ushort4*)out)[i] = o;
}

// ---------- RoPE tables ----------
__global__ void rope_table_k(float* __restrict__ cosT, float* __restrict__ sinT) {
    int id = blockIdx.x * 256 + threadIdx.x;   // 65536 total
    int l = id >> 5, i = id & 31;
    float freq = __expf(-(float)i * (9.210340371976184f / 32.0f));
    float ph = (float)l * freq;
    cosT[id] = cosf(ph);
    sinT[id] = sinf(ph);
}

// ---------- RoPE apply; Q scaled by (1/8)*log2(e) so attn can use exp2 ----------
__global__ void rope_apply_k(ushort* __restrict__ qkv, const float* __restrict__ cosT,
                             const float* __restrict__ sinT) {
    int id = blockIdx.x * 256 + threadIdx.x;   // 4096*40*32
    int i = id & 31;
    int hh = (id >> 5) % 40;
    int row = id / 1280;
    int l = row & 2047;
    size_t base = (size_t)row * 3072 + (hh < 32 ? hh * 64 : 2048 + (hh - 32) * 64);
    float c = cosT[(l << 5) + i], s = sinT[(l << 5) + i];
    float v1 = bf2f(qkv[base + i]), v2 = bf2f(qkv[base + 32 + i]);
    float scale = (hh < 32) ? 0.18033688f : 1.0f;   // 0.125 * log2(e)
    qkv[base + i]      = f2bf((c * v1 - s * v2) * scale);
    qkv[base + 32 + i] = f2bf((c * v2 + s * v1) * scale);
}

// ---------- transpose V ----------
__global__ void vtrans_k(const ushort* __restrict__ qkv, ushort* __restrict__ vt) {
    __shared__ __align__(16) ushort tile[64][72];
    int t = threadIdx.x;
    int l0 = blockIdx.x * 64, kh = blockIdx.y, b = blockIdx.z;
    int tr = t >> 3, tc = (t & 7) * 8;
#pragma unroll
    for (int i = 0; i < 2; ++i) {
        int l = i * 32 + tr;
        u16x8 v = *(const u16x8*)(qkv + (size_t)(b * 2048 + l0 + l) * 3072 + 2560 + kh * 64 + tc);
#pragma unroll
        for (int j = 0; j < 8; ++j) tile[tc + j][l] = v[j];
    }
    __syncthreads();
#pragma unroll
    for (int i = 0; i < 2; ++i) {
        int d = i * 32 + tr;
        u16x8 v = *(const u16x8*)&tile[d][tc];
        *(u16x8*)(vt + (size_t)((b * 8 + kh) * 64 + d) * 2048 + l0 + tc) = v;
    }
}

// ---------- 256x256-tile GEMM, 8 waves, BK=64, double-buffered counted-vmcnt pipeline ----------
// C[M,N] = A[M,K] * B[N,K]^T. LDS 128 KiB dynamic: As[2][256][64] + Bs[2][256][64], swizzled.
// Waves: 2(M) x 4(N); per-wave output 128x64 = 8x4 fragments of 16x16.
template <int F32OUT>
__global__ __launch_bounds__(512, 2) void gemm256(const ushort* __restrict__ A,
                                                  const ushort* __restrict__ B,
                                                  void* __restrict__ Cp, int M, int N, int K) {
    extern __shared__ __align__(16) ushort smem[];   // As: [0,32768), Bs: [32768,65536) elems
    ushort* As = smem;
    ushort* Bs = smem + 32768;
    const int tid = threadIdx.x, lane = tid & 63, wid = tid >> 6;
    const int wr = wid >> 2, wc = wid & 3;
    const int lr = lane & 15, lg = lane >> 4;
    const int m0 = blockIdx.y * 256, n0 = blockIdx.x * 256;
    const int NT = K >> 6;
    const int sr = tid >> 3;                         // 0..63
    const int sc = ((tid & 7) ^ (sr & 7)) << 3;      // pre-swizzled source col group
    const ushort* gA = A + (size_t)m0 * K;
    const ushort* gB = B + (size_t)n0 * K;

    auto stage = [&](const ushort* g, int t, ushort* lds) {   // 256x64 tile = 4 gloads
        const ushort* gs = g + (size_t)sr * K + t * 64 + sc;
        char* ld = (char*)lds + wid * 1024;
#pragma unroll
        for (int j = 0; j < 4; ++j)
            gload_lds16(gs + (size_t)(j * 64) * K, ld + j * 8192);
    };

    f32x4 acc[8][4] = {};
    stage(gA, 0, As);          stage(gB, 0, Bs);
    stage(gA, 1, As + 16384);  stage(gB, 1, Bs + 16384);
    asm volatile("s_waitcnt vmcnt(8)" ::: "memory");   // tile 0 landed; tile 1 in flight
    __builtin_amdgcn_s_barrier();

    for (int t = 0; t < NT; ++t) {
        const int c = t & 1;
        const ushort* Ac = As + c * 16384 + wr * 8192;            // wave's A half [128][64]
        const ushort* Bc = Bs + c * 16384 + (wc >> 1) * 8192;     // wave's B half [128][64]
        const int brow = (wc & 1) * 64;
        bf16x8 bfr[4][2];
#pragma unroll
        for (int nf = 0; nf < 4; ++nf)
#pragma unroll
            for (int kk = 0; kk < 2; ++kk)
                bfr[nf][kk] = *(const bf16x8*)&Bc[swz8(brow + nf * 16 + lr, kk * 4 + lg)];
#pragma unroll
        for (int h = 0; h < 2; ++h) {
            bf16x8 af[4][2];
#pragma unroll
            for (int mf = 0; mf < 4; ++mf)
#pragma unroll
                for (int kk = 0; kk < 2; ++kk)
                    af[mf][kk] = *(const bf16x8*)&Ac[swz8(h * 64 + mf * 16 + lr, kk * 4 + lg)];
            __builtin_amdgcn_s_setprio(1);
#pragma unroll
            for (int mf = 0; mf < 4; ++mf)
#pragma unroll
                for (int nf = 0; nf < 4; ++nf)
#pragma unroll
                    for (int kk = 0; kk < 2; ++kk)
                        acc[h * 4 + mf][nf] = MFMA16(af[mf][kk], bfr[nf][kk], acc[h * 4 + mf][nf]);
            __builtin_amdgcn_s_setprio(0);
        }
        __builtin_amdgcn_s_barrier();                 // all waves done reading buf c
        if (t + 2 < NT) {
            stage(gA, t + 2, As + c * 16384);         // overwrite just-freed buffer
            stage(gB, t + 2, Bs + c * 16384);
            asm volatile("s_waitcnt vmcnt(8)" ::: "memory");   // tile t+1 landed; t+2 in flight
        } else {
            asm volatile("s_waitcnt vmcnt(0)" ::: "memory");
        }
        __builtin_amdgcn_s_barrier();
    }

    const int r0 = m0 + wr * 128 + lg * 4;
    const int c0 = n0 + wc * 64 + lr;
    if (F32OUT) {
        float* C = (float*)Cp;
#pragma unroll
        for (int mi = 0; mi < 8; ++mi)
#pragma unroll
            for (int ni = 0; ni < 4; ++ni)
#pragma unroll
                for (int r = 0; r < 4; ++r)
                    C[(size_t)(r0 + mi * 16 + r) * N + c0 + ni * 16] = acc[mi][ni][r];
    } else {
        ushort* C = (ushort*)Cp;
#pragma unroll
        for (int mi = 0; mi < 8; ++mi)
#pragma unroll
            for (int ni = 0; ni < 4; ++ni)
#pragma unroll
                for (int r = 0; r < 4; ++r)
                    C[(size_t)(r0 + mi * 16 + r) * N + c0 + ni * 16] = f2bf(acc[mi][ni][r]);
    }
}

// ---------- flash attention: swapped QK^T, in-reg softmax, causal-PAIRED q-tiles ----------
// grid (8, 32, 2); block 256 = 4 waves. Block p processes q-tiles {15-p, p} sequentially:
// total kv-tile work = (2(15-p)+2) + (2p+2) = 34 for EVERY block -> perfectly balanced.
__global__ __launch_bounds__(256) void attn_k(const ushort* __restrict__ qkv,
                                              const ushort* __restrict__ vt,
                                              ushort* __restrict__ attn) {
    __shared__ __align__(16) ushort smem[16384];   // Ks[2]: bytes 0/8192, Vs[2]: 16384/24576
    const int tid = threadIdx.x, lane = tid & 63, wid = tid >> 6;
    const int hl = lane >> 5, lq = lane & 31;
    const int p = blockIdx.x;                     // 0..7
    const int head = blockIdx.y, b = blockIdx.z;
    const int kh = head >> 2;

    const ushort* Kg = qkv + (size_t)(b * 2048) * 3072 + 2048 + kh * 64;  // [kv][*] stride 3072
    const ushort* Vg = vt + (size_t)((b * 8 + kh) * 64) * 2048;           // [d][kv] stride 2048

    for (int ph = 0; ph < 2; ++ph) {
        const int qt = ph ? p : 15 - p;
        const int qb = qt << 7;
        const int qw0 = qb + wid * 32;
        const int q_lane = qw0 + lq;
        const int nt = 2 * qt + 2;

        // Q fragments: B-operand [col=q][k=d], d = j*16 + hl*8 + e
        bf16x8 qf[4];
        {
            const ushort* qp = qkv + (size_t)(b * 2048 + qw0 + lq) * 3072 + head * 64 + hl * 8;
#pragma unroll
            for (int j = 0; j < 4; ++j) qf[j] = *(const bf16x8*)(qp + j * 16);
        }
        f32x16 o0 = {}, o1 = {};     // O^T accum: d-tiles 0/1, col=q
        float m_ = -1e30f, lsum = 0.f;

        stage64(Kg, 3072, (char*)smem, tid);
        stage64(Vg, 2048, (char*)(smem + 8192), tid);

        for (int it = 0; it < nt; ++it) {
            const int c = it & 1;
            const int kv0 = it << 6;
            const ushort* Kc = smem + c * 4096;
            const ushort* Vc = smem + 8192 + c * 4096;
            if (it + 1 < nt) {
                stage64(Kg + (size_t)(kv0 + 64) * 3072, 3072, (char*)(smem + (c ^ 1) * 4096), tid);
                stage64(Vg + kv0 + 64, 2048, (char*)(smem + 8192 + (c ^ 1) * 4096), tid);
                asm volatile("s_waitcnt vmcnt(4)" ::: "memory");
            } else {
                asm volatile("s_waitcnt vmcnt(0)" ::: "memory");
            }
            __builtin_amdgcn_s_barrier();

            // S^T = K · Q^T : rows kv (2 subtiles), col q
            f32x16 s0 = {}, s1 = {};
            __builtin_amdgcn_s_setprio(1);
#pragma unroll
            for (int j = 0; j < 4; ++j) {
                bf16x8 k0 = *(const bf16x8*)&Kc[swz8(lq, j * 2 + hl)];
                bf16x8 k1 = *(const bf16x8*)&Kc[swz8(32 + lq, j * 2 + hl)];
                s0 = MFMA32(k0, qf[j], s0);
                s1 = MFMA32(k1, qf[j], s1);
            }
            __builtin_amdgcn_s_setprio(0);

            if (kv0 + 63 > qw0) {   // causal mask (wave-uniform branch)
#pragma unroll
                for (int i = 0; i < 16; ++i) {
                    int kvr = (i & 3) + ((i >> 2) << 3) + (hl << 2) + kv0;
                    if (kvr > q_lane)      s0[i] = -1e30f;
                    if (kvr + 32 > q_lane) s1[i] = -1e30f;
                }
            }
            // in-register softmax (log2 domain; scale folded into Q)
            float pmax = s0[0];
#pragma unroll
            for (int i = 1; i < 16; ++i) pmax = fmaxf(pmax, s0[i]);
#pragma unroll
            for (int i = 0; i < 16; ++i) pmax = fmaxf(pmax, s1[i]);
            {
                auto sw = __builtin_amdgcn_permlane32_swap(__float_as_int(pmax), __float_as_int(pmax), 0, 0);
                pmax = fmaxf(__int_as_float(sw[0]), __int_as_float(sw[1]));
            }
            if (!__all(pmax <= m_ + 8.0f)) {   // defer-max (T13)
                float mn = fmaxf(m_, pmax);
                float alpha = exp2f(m_ - mn);
                m_ = mn; lsum *= alpha;
#pragma unroll
                for (int i = 0; i < 16; ++i) { o0[i] *= alpha; o1[i] *= alpha; }
            }
            float rs = 0.f;
#pragma unroll
            for (int i = 0; i < 16; ++i) { s0[i] = exp2f(s0[i] - m_); rs += s0[i]; }
#pragma unroll
            for (int i = 0; i < 16; ++i) { s1[i] = exp2f(s1[i] - m_); rs += s1[i]; }
            {
                auto sw = __builtin_amdgcn_permlane32_swap(__float_as_int(rs), __float_as_int(rs), 0, 0);
                rs = __int_as_float(sw[0]) + __int_as_float(sw[1]);
            }
            lsum += rs;

            // P^T fragments: per 16-kv chunk, 4 cvt_pk + 2 permlane32_swap (T12)
            bf16x8 pf[4];
#pragma unroll
            for (int cc = 0; cc < 4; ++cc) {
                float p0, p1, p2, p3, p4, p5, p6, p7;
                if (cc == 0)      { p0=s0[0]; p1=s0[1]; p2=s0[2]; p3=s0[3]; p4=s0[4]; p5=s0[5]; p6=s0[6]; p7=s0[7]; }
                else if (cc == 1) { p0=s0[8]; p1=s0[9]; p2=s0[10]; p3=s0[11]; p4=s0[12]; p5=s0[13]; p6=s0[14]; p7=s0[15]; }
                else if (cc == 2) { p0=s1[0]; p1=s1[1]; p2=s1[2]; p3=s1[3]; p4=s1[4]; p5=s1[5]; p6=s1[6]; p7=s1[7]; }
                else              { p0=s1[8]; p1=s1[9]; p2=s1[10]; p3=s1[11]; p4=s1[12]; p5=s1[13]; p6=s1[14]; p7=s1[15]; }
                int pk01 = cvtpk(p0, p1), pk23 = cvtpk(p2, p3);
                int pk45 = cvtpk(p4, p5), pk67 = cvtpk(p6, p7);
                auto sA = __builtin_amdgcn_permlane32_swap(pk01, pk45, 0, 0);
                auto sB = __builtin_amdgcn_permlane32_swap(pk23, pk67, 0, 0);
                union { int w[4]; bf16x8 v; } u;
                u.w[0] = sA[0]; u.w[1] = sB[0]; u.w[2] = sA[1]; u.w[3] = sB[1];
                pf[cc] = u.v;
            }
            // O^T += V^T · P : A=V^T[d][kv] from LDS, B=P^T frag
            __builtin_amdgcn_s_setprio(1);
#pragma unroll
            for (int cc = 0; cc < 4; ++cc) {
                bf16x8 v0 = *(const bf16x8*)&Vc[swz8(lq, cc * 2 + hl)];
                bf16x8 v1 = *(const bf16x8*)&Vc[swz8(32 + lq, cc * 2 + hl)];
                o0 = MFMA32(v0, pf[cc], o0);
                o1 = MFMA32(v1, pf[cc], o1);
            }
            __builtin_amdgcn_s_setprio(0);
            __builtin_amdgcn_s_barrier();
        }

        // epilogue: O^T -> swizzled LDS transpose (per-wave 4KB in K-buffer area) -> b128 stores
        __syncthreads();
        ushort* sc = (ushort*)((char*)smem + wid * 4096);   // [32 q][64 d], XOR-group swizzled
        float inv = 1.0f / lsum;
#pragma unroll
        for (int i = 0; i < 16; i += 2) {
            int d0 = (i & 3) + ((i >> 2) << 3) + (hl << 2);
            int g0 = d0 >> 3, g1 = (d0 + 32) >> 3;
            *(int*)&sc[lq * 64 + ((g0 ^ (lq & 7)) << 3) + (d0 & 7)] = cvtpk(o0[i] * inv, o0[i + 1] * inv);
            *(int*)&sc[lq * 64 + ((g1 ^ (lq & 7)) << 3) + (d0 & 7)] = cvtpk(o1[i] * inv, o1[i + 1] * inv);
        }
        __syncthreads();
        {
            const int q = lane >> 1, db = (lane & 1) << 5;
            const size_t orow = (size_t)(b * 2048 + qb + wid * 32 + q);
#pragma unroll
            for (int j = 0; j < 4; ++j) {
                int g = (db >> 3) + j;
                u16x8 v = *(const u16x8*)&sc[q * 64 + ((g ^ (q & 7)) << 3)];
                *(u16x8*)(attn + orow * 2048 + head * 64 + g * 8) = v;
            }
        }
        __syncthreads();   // sc reads done before next phase re-stages this LDS
    }
}

// ---------- launch ----------
extern "C" void kernel_launch(void* const* d_in, const int* in_sizes, int n_in,
                              void* d_out, int out_size, void* d_ws, size_t ws_size,
                              hipStream_t stream) {
    const float* x  = (const float*)d_in[0];
    const float* wq = (const float*)d_in[1];
    const float* wk = (const float*)d_in[2];
    const float* wv = (const float*)d_in[3];
    const float* wo = (const float*)d_in[4];
    float* out = (float*)d_out;
    char* ws = (char*)d_ws;

    ushort* xb   = (ushort*)(ws);                 // 16 MB
    ushort* wcat = (ushort*)(ws + 16777216);      // 12 MB
    ushort* wob  = (ushort*)(ws + 29360128);      // 8 MB
    ushort* qkv  = (ushort*)(ws + 37748736);      // 24 MB
    ushort* vt   = (ushort*)(ws + 62914560);      // 4 MB
    ushort* attn = (ushort*)(ws + 67108864);      // 16 MB
    float*  cosT = (float*)(ws + 83886080);
    float*  sinT = (float*)(ws + 84148224);

    // allow 128 KiB dynamic LDS for the 256^2 GEMM (idempotent, capture-safe)
    (void)hipFuncSetAttribute((const void*)gemm256<0>,
                              hipFuncAttributeMaxDynamicSharedMemorySize, 131072);
    (void)hipFuncSetAttribute((const void*)gemm256<1>,
                              hipFuncAttributeMaxDynamicSharedMemorySize, 131072);

    {
        int n4;
        n4 = 8388608 >> 2; cvt_f32_bf16<<<(n4 + 255) / 256, 256, 0, stream>>>(x, xb, n4);
        n4 = 4194304 >> 2; cvt_f32_bf16<<<(n4 + 255) / 256, 256, 0, stream>>>(wq, wcat, n4);
        n4 = 1048576 >> 2; cvt_f32_bf16<<<(n4 + 255) / 256, 256, 0, stream>>>(wk, wcat + 4194304, n4);
        n4 = 1048576 >> 2; cvt_f32_bf16<<<(n4 + 255) / 256, 256, 0, stream>>>(wv, wcat + 5242880, n4);
        n4 = 4194304 >> 2; cvt_f32_bf16<<<(n4 + 255) / 256, 256, 0, stream>>>(wo, wob, n4);
    }
    rope_table_k<<<256, 256, 0, stream>>>(cosT, sinT);
    // QKV projection: [4096,2048] x [3072,2048]^T -> qkv bf16   (192 blocks, 1/CU)
    gemm256<0><<<dim3(12, 16), 512, 131072, stream>>>(xb, wcat, qkv, 4096, 3072, 2048);
    rope_apply_k<<<20480, 256, 0, stream>>>(qkv, cosT, sinT);
    vtrans_k<<<dim3(32, 8, 2), 256, 0, stream>>>(qkv, vt);
    attn_k<<<dim3(8, 32, 2), 256, 0, stream>>>(qkv, vt, attn);
    // output projection -> fp32 d_out   (128 blocks, 1/CU)
    gemm256<1><<<dim3(8, 16), 512, 131072, stream>>>(attn, wob, out, 4096, 2048, 2048);
}

// Round 6
// 214.535 us; speedup vs baseline: 2.1088x; 1.1392x over previous
//
#include <hip/hip_runtime.h>

// ---------- types / helpers ----------
typedef __attribute__((ext_vector_type(8))) __bf16 bf16x8;
typedef __attribute__((ext_vector_type(8))) ushort u16x8;
typedef __attribute__((ext_vector_type(4))) float f32x4;
typedef __attribute__((ext_vector_type(16))) float f32x16;

#define MFMA16(a, b, c) __builtin_amdgcn_mfma_f32_16x16x32_bf16(a, b, c, 0, 0, 0)
#define MFMA32(a, b, c) __builtin_amdgcn_mfma_f32_32x32x16_bf16(a, b, c, 0, 0, 0)

__device__ __forceinline__ ushort f2bf(float f) {
    union { float f; unsigned u; } v; v.f = f;
    unsigned r = v.u + 0x7FFFu + ((v.u >> 16) & 1u);
    return (ushort)(r >> 16);
}
__device__ __forceinline__ float bf2f(ushort b) {
    union { unsigned u; float f; } v; v.u = ((unsigned)b) << 16; return v.f;
}
__device__ __forceinline__ int cvtpk(float lo, float hi) {
    int r; asm("v_cvt_pk_bf16_f32 %0, %1, %2" : "=v"(r) : "v"(lo), "v"(hi)); return r;
}
__device__ __forceinline__ void gload_lds16(const void* g, void* l) {
    __builtin_amdgcn_global_load_lds((const __attribute__((address_space(1))) void*)g,
                                     (__attribute__((address_space(3))) void*)l, 16, 0, 0);
}

// swizzle for [*,64]-element bf16 rows (attn tiles): 16B group g of row at g^(row&7)
__device__ __forceinline__ int swz8(int row, int g) {
    return row * 64 + (((g) ^ (row & 7)) << 3);
}

// ---------- fp32 -> bf16 convert ----------
__global__ void cvt_f32_bf16(const float* __restrict__ in, ushort* __restrict__ out, int n4) {
    int i = blockIdx.x * blockDim.x + threadIdx.x;
    if (i >= n4) return;
    float4 v = ((const float4*)in)[i];
    ushort4 o;
    o.x = f2bf(v.x); o.y = f2bf(v.y); o.z = f2bf(v.z); o.w = f2bf(v.w);
    ((ushort4*)out)[i] = o;
}

// ---------- RoPE tables, TRANSPOSED layout [32][2048] for epilogue float4 loads ----------
__global__ void rope_table_k(float* __restrict__ cosT, float* __restrict__ sinT) {
    int id = blockIdx.x * 256 + threadIdx.x;   // 65536 = 32*2048
    int i = id >> 11, l = id & 2047;
    float freq = __expf(-(float)i * (9.210340371976184f / 32.0f));
    float ph = (float)l * freq;
    cosT[id] = cosf(ph);
    sinT[id] = sinf(ph);
}

// ---------- fused GEMM: C[M,N]=A[M,K]*B[N,K]^T, BK=32, 3-buffer interleaved pipeline ----------
// EPI=1: f32 plain out. EPI=2: QKV-fused (RoPE on Q[scaled]/K -> qkv, V transposed -> vt).
// 8 waves WM x WN; per-wave out (256/WM) x (BN/WN). LDS: 3*(256*32) A + 3*(BN*32) B.
template <int EPI, int BN, int WM, int WN>
__global__ __launch_bounds__(512, 2) void gemmK(const ushort* __restrict__ A,
                                                const ushort* __restrict__ B,
                                                void* __restrict__ Cp,
                                                ushort* __restrict__ vt,
                                                const float* __restrict__ cosT,
                                                const float* __restrict__ sinT,
                                                int M, int N, int K) {
    constexpr int MF = 256 / WM / 16;
    constexpr int NF = BN / WN / 16;
    constexpr int BLOADS = BN / 128;            // B gloads per K-tile
    constexpr int TLOADS = 2 + BLOADS;          // loads per K-tile
    constexpr int ABUF = 256 * 32;
    constexpr int BBUF = BN * 32;
    extern __shared__ __align__(16) ushort sm[];
    ushort* sA = sm;                  // 3 * ABUF
    ushort* sB = sm + 3 * ABUF;       // 3 * BBUF
    const int tid = threadIdx.x, lane = tid & 63, wid = tid >> 6;
    const int wr = wid / WN, wc = wid % WN;
    const int lr = lane & 15, lg = lane >> 4;
    const int m0 = blockIdx.y * 256, n0 = blockIdx.x * BN;
    const int NT = K >> 5;
    // staging: thread covers row tid>>2 (+128), source col-group pre-swizzled (BK=32: g^((row>>1)&3))
    const int csrc = ((tid & 3) ^ ((tid >> 3) & 3)) << 3;
    const int co = ((lg ^ ((lr >> 1) & 3)) << 3);   // swizzled frag-read col offset
    const ushort* gAt = A + (size_t)(m0 + (tid >> 2)) * K + csrc;
    const ushort* gBt = B + (size_t)(n0 + (tid >> 2)) * K + csrc;

    auto stgA = [&](int t, int buf) {
        const ushort* g = gAt + t * 32;
        char* ld = (char*)(sA + buf * ABUF) + wid * 1024;
        gload_lds16(g, ld);
        gload_lds16(g + (size_t)128 * K, ld + 8192);
    };
    auto stgB = [&](int t, int buf) {
        const ushort* g = gBt + t * 32;
        char* ld = (char*)(sB + buf * BBUF) + wid * 1024;
        gload_lds16(g, ld);
        if constexpr (BLOADS == 2) gload_lds16(g + (size_t)128 * K, ld + 8192);
    };

    f32x4 acc[MF][NF] = {};
    stgA(0, 0); stgB(0, 0); stgA(1, 1); stgB(1, 1);
    if constexpr (TLOADS == 4) asm volatile("s_waitcnt vmcnt(4)" ::: "memory");
    else                       asm volatile("s_waitcnt vmcnt(3)" ::: "memory");
    __builtin_amdgcn_s_barrier();

    int cur = 0, stg = 2;
    for (int t = 0; t < NT; ++t) {
        const ushort* Ac = sA + cur * ABUF + (wr * (256 / WM)) * 32 + co;
        const ushort* Bc = sB + cur * BBUF + (wc * (BN / WN)) * 32 + co;
        if constexpr (BN == 256) {
            // ---- phase 1: B frags + A half 1, stage A(t+2), 16 MFMA ----
            bf16x8 bfr[NF], af[MF / 2];
#pragma unroll
            for (int nf = 0; nf < NF; ++nf) bfr[nf] = *(const bf16x8*)&Bc[(nf * 16 + lr) * 32];
#pragma unroll
            for (int mf = 0; mf < MF / 2; ++mf) af[mf] = *(const bf16x8*)&Ac[(mf * 16 + lr) * 32];
            if (t + 2 < NT) stgA(t + 2, stg);
            __builtin_amdgcn_s_barrier();
            __builtin_amdgcn_s_setprio(1);
#pragma unroll
            for (int mf = 0; mf < MF / 2; ++mf)
#pragma unroll
                for (int nf = 0; nf < NF; ++nf)
                    acc[mf][nf] = MFMA16(af[mf], bfr[nf], acc[mf][nf]);
            __builtin_amdgcn_s_setprio(0);
            __builtin_amdgcn_s_barrier();
            // ---- phase 2: A half 2, stage B(t+2), counted vmcnt, 16 MFMA ----
            bf16x8 af2[MF - MF / 2];
#pragma unroll
            for (int mf = 0; mf < MF - MF / 2; ++mf)
                af2[mf] = *(const bf16x8*)&Ac[((mf + MF / 2) * 16 + lr) * 32];
            if (t + 2 < NT) {
                stgB(t + 2, stg);
                asm volatile("s_waitcnt vmcnt(4)" ::: "memory");   // t+1 landed; t+2 in flight
            } else {
                asm volatile("s_waitcnt vmcnt(0)" ::: "memory");
            }
            __builtin_amdgcn_s_barrier();
            __builtin_amdgcn_s_setprio(1);
#pragma unroll
            for (int mf = 0; mf < MF - MF / 2; ++mf)
#pragma unroll
                for (int nf = 0; nf < NF; ++nf)
                    acc[mf + MF / 2][nf] = MFMA16(af2[mf], bfr[nf], acc[mf + MF / 2][nf]);
            __builtin_amdgcn_s_setprio(0);
            __builtin_amdgcn_s_barrier();
        } else {
            // ---- single phase: all frags, stage A+B(t+2), counted vmcnt, 16 MFMA ----
            bf16x8 bfr[NF], af[MF];
#pragma unroll
            for (int nf = 0; nf < NF; ++nf) bfr[nf] = *(const bf16x8*)&Bc[(nf * 16 + lr) * 32];
#pragma unroll
            for (int mf = 0; mf < MF; ++mf) af[mf] = *(const bf16x8*)&Ac[(mf * 16 + lr) * 32];
            if (t + 2 < NT) {
                stgA(t + 2, stg); stgB(t + 2, stg);
                asm volatile("s_waitcnt vmcnt(3)" ::: "memory");
            } else {
                asm volatile("s_waitcnt vmcnt(0)" ::: "memory");
            }
            __builtin_amdgcn_s_barrier();
            __builtin_amdgcn_s_setprio(1);
#pragma unroll
            for (int mf = 0; mf < MF; ++mf)
#pragma unroll
                for (int nf = 0; nf < NF; ++nf)
                    acc[mf][nf] = MFMA16(af[mf], bfr[nf], acc[mf][nf]);
            __builtin_amdgcn_s_setprio(0);
            __builtin_amdgcn_s_barrier();
        }
        cur = (cur == 2) ? 0 : cur + 1;
        stg = (stg == 2) ? 0 : stg + 1;
    }

    const int r0 = m0 + wr * (256 / WM) + lg * 4;
    const int c0 = n0 + wc * (BN / WN) + lr;
    if constexpr (EPI == 1) {
        float* C = (float*)Cp;
#pragma unroll
        for (int mi = 0; mi < MF; ++mi)
#pragma unroll
            for (int ni = 0; ni < NF; ++ni)
#pragma unroll
                for (int r = 0; r < 4; ++r)
                    C[(size_t)(r0 + mi * 16 + r) * N + c0 + ni * 16] = acc[mi][ni][r];
    } else {
        // fused QKV epilogue. wave col-chunk (64 cols) is head-aligned & region-uniform.
        const int wavecol = n0 + wc * (BN / WN);
        ushort* qkv = (ushort*)Cp;
        if (wavecol >= 2560) {
            // V: transpose-scatter to vt[(b*8+kh)*64+d][l]
            const int kh = (wavecol - 2560) >> 6;
            const int b = m0 >> 11;
            const int l0 = r0 & 2047;
#pragma unroll
            for (int ni = 0; ni < NF; ++ni) {
                const int d = lr + ni * 16;
                ushort* vrow = vt + (size_t)((b * 8 + kh) * 64 + d) * 2048 + l0;
#pragma unroll
                for (int mi = 0; mi < MF; ++mi) {
                    ushort4 o;
                    o.x = f2bf(acc[mi][ni][0]); o.y = f2bf(acc[mi][ni][1]);
                    o.z = f2bf(acc[mi][ni][2]); o.w = f2bf(acc[mi][ni][3]);
                    *(ushort4*)(vrow + mi * 16) = o;
                }
            }
        } else {
            // Q (scaled by 0.125*log2e) or K: RoPE pairs (ni, ni+2) are lane-local
            const float scale = (wavecol < 2048) ? 0.18033688f : 1.0f;
            const int l0 = r0 & 2047;
#pragma unroll
            for (int ni = 0; ni < NF / 2; ++ni) {
                const int i = ni * 16 + lr;   // 0..31
                const float* cp = cosT + i * 2048 + l0;
                const float* sp = sinT + i * 2048 + l0;
#pragma unroll
                for (int mi = 0; mi < MF; ++mi) {
                    float4 cv = *(const float4*)(cp + mi * 16);
                    float4 sv = *(const float4*)(sp + mi * 16);
#pragma unroll
                    for (int r = 0; r < 4; ++r) {
                        float lo = acc[mi][ni][r], hi = acc[mi][ni + 2][r];
                        float c = ((const float*)&cv)[r], s = ((const float*)&sv)[r];
                        size_t row = (size_t)(r0 + mi * 16 + r) * 3072;
                        qkv[row + c0 + ni * 16]      = f2bf((c * lo - s * hi) * scale);
                        qkv[row + c0 + ni * 16 + 32] = f2bf((c * hi + s * lo) * scale);
                    }
                }
            }
        }
    }
}

// ---------- flash attention: swapped QK^T, in-reg softmax, causal-PAIRED q-tiles ----------
__global__ __launch_bounds__(256) void attn_k(const ushort* __restrict__ qkv,
                                              const ushort* __restrict__ vt,
                                              ushort* __restrict__ attn) {
    __shared__ __align__(16) ushort smem[16384];
    const int tid = threadIdx.x, lane = tid & 63, wid = tid >> 6;
    const int hl = lane >> 5, lq = lane & 31;
    const int p = blockIdx.x;
    const int head = blockIdx.y, b = blockIdx.z;
    const int kh = head >> 2;

    const ushort* Kg = qkv + (size_t)(b * 2048) * 3072 + 2048 + kh * 64;
    const ushort* Vg = vt + (size_t)((b * 8 + kh) * 64) * 2048;
    const int c8 = ((tid & 7) ^ ((tid >> 3) & 7)) << 3;
    const ushort* kbase = Kg + (size_t)(tid >> 3) * 3072 + c8;
    const ushort* vbase = Vg + (size_t)(tid >> 3) * 2048 + c8;

    for (int ph = 0; ph < 2; ++ph) {
        const int qt = ph ? p : 15 - p;
        const int qb = qt << 7;
        const int qw0 = qb + wid * 32;
        const int q_lane = qw0 + lq;
        const int nt = 2 * qt + 2;

        bf16x8 qf[4];
        {
            const ushort* qp = qkv + (size_t)(b * 2048 + qw0 + lq) * 3072 + head * 64 + hl * 8;
#pragma unroll
            for (int j = 0; j < 4; ++j) qf[j] = *(const bf16x8*)(qp + j * 16);
        }
        f32x16 o0 = {}, o1 = {};
        float m_ = -1e30f, lsum = 0.f;

        // prologue stage tile 0; running next-tile pointers avoid per-iter addr mul
        gload_lds16(kbase, (char*)smem + wid * 1024);
        gload_lds16(kbase + (size_t)32 * 3072, (char*)smem + 4096 + wid * 1024);
        gload_lds16(vbase, (char*)(smem + 8192) + wid * 1024);
        gload_lds16(vbase + (size_t)32 * 2048, (char*)(smem + 8192) + 4096 + wid * 1024);
        const ushort* kn = kbase + (size_t)64 * 3072;
        const ushort* vn = vbase + 64;

        for (int it = 0; it < nt; ++it) {
            const int c = it & 1;
            const int kv0 = it << 6;
            const ushort* Kc = smem + c * 4096;
            const ushort* Vc = smem + 8192 + c * 4096;
            if (it + 1 < nt) {
                char* kd = (char*)smem + (c ^ 1) * 8192;
                char* vd = (char*)(smem + 8192) + (c ^ 1) * 8192;
                gload_lds16(kn, kd + wid * 1024);
                gload_lds16(kn + (size_t)32 * 3072, kd + 4096 + wid * 1024);
                gload_lds16(vn, vd + wid * 1024);
                gload_lds16(vn + (size_t)32 * 2048, vd + 4096 + wid * 1024);
                kn += (size_t)64 * 3072; vn += 64;
                asm volatile("s_waitcnt vmcnt(4)" ::: "memory");
            } else {
                asm volatile("s_waitcnt vmcnt(0)" ::: "memory");
            }
            __builtin_amdgcn_s_barrier();

            f32x16 s0 = {}, s1 = {};
            __builtin_amdgcn_s_setprio(1);
#pragma unroll
            for (int j = 0; j < 4; ++j) {
                bf16x8 k0 = *(const bf16x8*)&Kc[swz8(lq, j * 2 + hl)];
                bf16x8 k1 = *(const bf16x8*)&Kc[swz8(32 + lq, j * 2 + hl)];
                s0 = MFMA32(k0, qf[j], s0);
                s1 = MFMA32(k1, qf[j], s1);
            }
            __builtin_amdgcn_s_setprio(0);

            if (kv0 + 63 > qw0) {
#pragma unroll
                for (int i = 0; i < 16; ++i) {
                    int kvr = (i & 3) + ((i >> 2) << 3) + (hl << 2) + kv0;
                    if (kvr > q_lane)      s0[i] = -1e30f;
                    if (kvr + 32 > q_lane) s1[i] = -1e30f;
                }
            }
            // max via 3-ary tree (v_max3 fusion), short dep chain
#define F3(a, b, cc) fmaxf(fmaxf((a), (b)), (cc))
            float a0 = F3(s0[0], s0[1], s0[2]),  a1 = F3(s0[3], s0[4], s0[5]);
            float a2 = F3(s0[6], s0[7], s0[8]),  a3 = F3(s0[9], s0[10], s0[11]);
            float a4 = F3(s0[12], s0[13], s0[14]), a5 = F3(s0[15], s1[0], s1[1]);
            float a6 = F3(s1[2], s1[3], s1[4]),  a7 = F3(s1[5], s1[6], s1[7]);
            float a8 = F3(s1[8], s1[9], s1[10]), a9 = F3(s1[11], s1[12], s1[13]);
            float aA = fmaxf(s1[14], s1[15]);
            float b0 = F3(a0, a1, a2), b1 = F3(a3, a4, a5), b2 = F3(a6, a7, a8);
            float pmax = F3(b0, b1, b2);
            pmax = F3(pmax, a9, aA);
#undef F3
            {
                auto sw = __builtin_amdgcn_permlane32_swap(__float_as_int(pmax), __float_as_int(pmax), 0, 0);
                pmax = fmaxf(__int_as_float(sw[0]), __int_as_float(sw[1]));
            }
            if (!__all(pmax <= m_ + 8.0f)) {
                float mn = fmaxf(m_, pmax);
                float alpha = exp2f(m_ - mn);
                m_ = mn; lsum *= alpha;
#pragma unroll
                for (int i = 0; i < 16; ++i) { o0[i] *= alpha; o1[i] *= alpha; }
            }
#pragma unroll
            for (int i = 0; i < 16; ++i) s0[i] = exp2f(s0[i] - m_);
#pragma unroll
            for (int i = 0; i < 16; ++i) s1[i] = exp2f(s1[i] - m_);
            // sum: vector add + pairwise tree (log depth)
            f32x16 ts = s0 + s1;
            float u0 = ts[0] + ts[1], u1 = ts[2] + ts[3], u2 = ts[4] + ts[5], u3 = ts[6] + ts[7];
            float u4 = ts[8] + ts[9], u5 = ts[10] + ts[11], u6 = ts[12] + ts[13], u7 = ts[14] + ts[15];
            float w0 = u0 + u1, w1 = u2 + u3, w2 = u4 + u5, w3 = u6 + u7;
            float rs = (w0 + w1) + (w2 + w3);
            {
                auto sw = __builtin_amdgcn_permlane32_swap(__float_as_int(rs), __float_as_int(rs), 0, 0);
                rs = __int_as_float(sw[0]) + __int_as_float(sw[1]);
            }
            lsum += rs;

            bf16x8 pf[4];
#pragma unroll
            for (int cc = 0; cc < 4; ++cc) {
                float p0, p1, p2, p3, p4, p5, p6, p7;
                if (cc == 0)      { p0=s0[0]; p1=s0[1]; p2=s0[2]; p3=s0[3]; p4=s0[4]; p5=s0[5]; p6=s0[6]; p7=s0[7]; }
                else if (cc == 1) { p0=s0[8]; p1=s0[9]; p2=s0[10]; p3=s0[11]; p4=s0[12]; p5=s0[13]; p6=s0[14]; p7=s0[15]; }
                else if (cc == 2) { p0=s1[0]; p1=s1[1]; p2=s1[2]; p3=s1[3]; p4=s1[4]; p5=s1[5]; p6=s1[6]; p7=s1[7]; }
                else              { p0=s1[8]; p1=s1[9]; p2=s1[10]; p3=s1[11]; p4=s1[12]; p5=s1[13]; p6=s1[14]; p7=s1[15]; }
                int pk01 = cvtpk(p0, p1), pk23 = cvtpk(p2, p3);
                int pk45 = cvtpk(p4, p5), pk67 = cvtpk(p6, p7);
                auto sA = __builtin_amdgcn_permlane32_swap(pk01, pk45, 0, 0);
                auto sB = __builtin_amdgcn_permlane32_swap(pk23, pk67, 0, 0);
                union { int w[4]; bf16x8 v; } u;
                u.w[0] = sA[0]; u.w[1] = sB[0]; u.w[2] = sA[1]; u.w[3] = sB[1];
                pf[cc] = u.v;
            }
            __builtin_amdgcn_s_setprio(1);
#pragma unroll
            for (int cc = 0; cc < 4; ++cc) {
                bf16x8 v0 = *(const bf16x8*)&Vc[swz8(lq, cc * 2 + hl)];
                bf16x8 v1 = *(const bf16x8*)&Vc[swz8(32 + lq, cc * 2 + hl)];
                o0 = MFMA32(v0, pf[cc], o0);
                o1 = MFMA32(v1, pf[cc], o1);
            }
            __builtin_amdgcn_s_setprio(0);
            __builtin_amdgcn_s_barrier();
        }

        __syncthreads();
        ushort* sc = (ushort*)((char*)smem + wid * 4096);
        float inv = 1.0f / lsum;
#pragma unroll
        for (int i = 0; i < 16; i += 2) {
            int d0 = (i & 3) + ((i >> 2) << 3) + (hl << 2);
            int g0 = d0 >> 3, g1 = (d0 + 32) >> 3;
            *(int*)&sc[lq * 64 + ((g0 ^ (lq & 7)) << 3) + (d0 & 7)] = cvtpk(o0[i] * inv, o0[i + 1] * inv);
            *(int*)&sc[lq * 64 + ((g1 ^ (lq & 7)) << 3) + (d0 & 7)] = cvtpk(o1[i] * inv, o1[i + 1] * inv);
        }
        __syncthreads();
        {
            const int q = lane >> 1, db = (lane & 1) << 5;
            const size_t orow = (size_t)(b * 2048 + qb + wid * 32 + q);
#pragma unroll
            for (int j = 0; j < 4; ++j) {
                int g = (db >> 3) + j;
                u16x8 v = *(const u16x8*)&sc[q * 64 + ((g ^ (q & 7)) << 3)];
                *(u16x8*)(attn + orow * 2048 + head * 64 + g * 8) = v;
            }
        }
        __syncthreads();
    }
}

// ---------- launch ----------
extern "C" void kernel_launch(void* const* d_in, const int* in_sizes, int n_in,
                              void* d_out, int out_size, void* d_ws, size_t ws_size,
                              hipStream_t stream) {
    const float* x  = (const float*)d_in[0];
    const float* wq = (const float*)d_in[1];
    const float* wk = (const float*)d_in[2];
    const float* wv = (const float*)d_in[3];
    const float* wo = (const float*)d_in[4];
    float* out = (float*)d_out;
    char* ws = (char*)d_ws;

    ushort* xb   = (ushort*)(ws);                 // 16 MB
    ushort* wcat = (ushort*)(ws + 16777216);      // 12 MB
    ushort* wob  = (ushort*)(ws + 29360128);      // 8 MB
    ushort* qkv  = (ushort*)(ws + 37748736);      // 24 MB
    ushort* vt   = (ushort*)(ws + 62914560);      // 4 MB
    ushort* attn = (ushort*)(ws + 67108864);      // 16 MB
    float*  cosT = (float*)(ws + 83886080);       // [32][2048] f32
    float*  sinT = (float*)(ws + 84148224);

    (void)hipFuncSetAttribute((const void*)gemmK<2, 256, 2, 4>,
                              hipFuncAttributeMaxDynamicSharedMemorySize, 98304);
    (void)hipFuncSetAttribute((const void*)gemmK<1, 128, 4, 2>,
                              hipFuncAttributeMaxDynamicSharedMemorySize, 73728);

    {
        int n4;
        n4 = 8388608 >> 2; cvt_f32_bf16<<<(n4 + 255) / 256, 256, 0, stream>>>(x, xb, n4);
        n4 = 4194304 >> 2; cvt_f32_bf16<<<(n4 + 255) / 256, 256, 0, stream>>>(wq, wcat, n4);
        n4 = 1048576 >> 2; cvt_f32_bf16<<<(n4 + 255) / 256, 256, 0, stream>>>(wk, wcat + 4194304, n4);
        n4 = 1048576 >> 2; cvt_f32_bf16<<<(n4 + 255) / 256, 256, 0, stream>>>(wv, wcat + 5242880, n4);
        n4 = 4194304 >> 2; cvt_f32_bf16<<<(n4 + 255) / 256, 256, 0, stream>>>(wo, wob, n4);
    }
    rope_table_k<<<256, 256, 0, stream>>>(cosT, sinT);
    // QKV projection + fused RoPE + V-transpose  (192 blocks)
    gemmK<2, 256, 2, 4><<<dim3(12, 16), 512, 98304, stream>>>(xb, wcat, qkv, vt, cosT, sinT,
                                                              4096, 3072, 2048);
    // flash attention
    attn_k<<<dim3(8, 32, 2), 256, 0, stream>>>(qkv, vt, attn);
    // output projection -> fp32 d_out  (256 blocks, full chip)
    gemmK<1, 128, 4, 2><<<dim3(16, 16), 512, 73728, stream>>>(attn, wob, out, nullptr, nullptr,
                                                              nullptr, 4096, 2048, 2048);
}